// Round 2
// baseline (3259.657 us; speedup 1.0000x reference)
//
#include <hip/hip_runtime.h>

// B=4, T=128, N=512, D=32, CHEB_K=3, EMB=10, HEADS=2, TA_LAYERS=2, GCN_NUM=3,
// TCN_BLOCKS=3, KSIZE=3.  All inputs/outputs fp32; internal staging bf16.

__device__ __forceinline__ unsigned short f2b(float f) {
  unsigned int x = __float_as_uint(f);
  unsigned int r = (x + 0x7fffu + ((x >> 16) & 1u)) >> 16;
  return (unsigned short)r;
}
__device__ __forceinline__ float b2f(unsigned short u) {
  return __uint_as_float(((unsigned int)u) << 16);
}
__device__ __forceinline__ float2 bpair(unsigned int p) {
  float2 r;
  r.x = __uint_as_float(p << 16);
  r.y = __uint_as_float(p & 0xffff0000u);
  return r;
}
__device__ __forceinline__ float4 bquad(uint2 p) {
  float4 r;
  r.x = __uint_as_float(p.x << 16);
  r.y = __uint_as_float(p.x & 0xffff0000u);
  r.z = __uint_as_float(p.y << 16);
  r.w = __uint_as_float(p.y & 0xffff0000u);
  return r;
}
__device__ __forceinline__ float4 fma4(float4 a, float s, float4 h) {
  a.x += s * h.x; a.y += s * h.y; a.z += s * h.z; a.w += s * h.w; return a;
}

// ---------------- prep: second Chebyshev support ----------------
// s2f = 2*adj@adj - I   (adj fp32 input used directly as support 1)
__global__ void __launch_bounds__(256) prep_adj_kernel(
    const float* __restrict__ adj, float* __restrict__ s2f) {
  __shared__ float arow[512];
  int n = blockIdx.x, tid = threadIdx.x;
  for (int m = tid; m < 512; m += 256) arow[m] = adj[n * 512 + m];
  __syncthreads();
  for (int m = tid; m < 512; m += 256) {
    float acc = 0.f;
    for (int p = 0; p < 512; ++p) acc += arow[p] * adj[p * 512 + m];
    s2f[n * 512 + m] = 2.f * acc - (m == n ? 1.f : 0.f);
  }
}

// ---------------- prep: per-node GCN weights ----------------
// Wn[i][n][k][o][c] = sum_e E[n,e] * gcn_w[i,e,k,c,o]   (transposed o,c)
// biasn[i][n][o]    = sum_e E[n,e] * gcn_b[i,e,o]
__global__ void __launch_bounds__(256) prep_w_kernel(
    const float* __restrict__ emb,  // (512,10)
    const float* __restrict__ gw,   // (3,10,3,32,32) = [i][e][k][c][o]
    const float* __restrict__ gb,   // (3,10,32)
    float* __restrict__ Wn, float* __restrict__ biasn) {
  int bid = blockIdx.x;  // 0..1535
  int i = bid >> 9, n = bid & 511, tid = threadIdx.x;
  float ev[10];
#pragma unroll
  for (int e = 0; e < 10; ++e) ev[e] = emb[n * 10 + e];
  for (int idx = tid; idx < 3072; idx += 256) {
    int kk = idx >> 10, rem = idx & 1023;
    int o = rem >> 5, c = rem & 31;
    float acc = 0.f;
#pragma unroll
    for (int e = 0; e < 10; ++e)
      acc += ev[e] * gw[(((i * 10 + e) * 3 + kk) << 10) + (c << 5) + o];
    Wn[(((i * 512 + n) * 3 + kk) << 10) + rem] = acc;
  }
  if (tid < 32) {
    float acc = 0.f;
#pragma unroll
    for (int e = 0; e < 10; ++e) acc += ev[e] * gb[(i * 10 + e) * 32 + tid];
    biasn[(i * 512 + n) * 32 + tid] = acc;
  }
}

// ---------------- GCN layer ----------------
// One block per bt. LDS: h tile bf16 (512x32=32KB), g1/g2 fp32 (8KB each).
__global__ void __launch_bounds__(256) gcn_kernel(
    const float* __restrict__ hin, float* __restrict__ hout,
    const float* __restrict__ Wn,     // layer base: [512][3][32(o)][32(c)]
    const float* __restrict__ biasn,  // layer base: [512][32]
    const float* __restrict__ adjf, const float* __restrict__ s2f) {
  __shared__ unsigned short hs[512 * 32];
  __shared__ float g1[64 * 32];
  __shared__ float g2[64 * 32];
  int bt = blockIdx.x, tid = threadIdx.x;
  for (int idx = tid; idx < 16384; idx += 256) hs[idx] = f2b(hin[bt * 16384 + idx]);
  __syncthreads();
  const int s = tid >> 7, cg = tid & 7, ng = (tid >> 3) & 15;
  const float4* A4 = (const float4*)(s ? s2f : adjf);
  float* gbuf = s ? g2 : g1;
  const int o = tid & 31, nl0 = tid >> 5;
  for (int chunk = 0; chunk < 8; ++chunk) {
    // phase A: g[n][c] = sum_m A[n][m]*h[m][c] for this 64-node chunk
    int n0 = chunk * 64 + ng * 4;
    float4 z = {0.f, 0.f, 0.f, 0.f};
    float4 acc0 = z, acc1 = z, acc2 = z, acc3 = z;
#pragma unroll 4
    for (int m4 = 0; m4 < 128; ++m4) {
      float4 a0 = A4[(n0 + 0) * 128 + m4];
      float4 a1 = A4[(n0 + 1) * 128 + m4];
      float4 a2 = A4[(n0 + 2) * 128 + m4];
      float4 a3 = A4[(n0 + 3) * 128 + m4];
      const uint2* hp = (const uint2*)&hs[(m4 * 4) * 32 + cg * 4];
      float4 h0 = bquad(hp[0]);  // row stride 32 ushorts = 8 uint2
      float4 h1 = bquad(hp[8]);
      float4 h2 = bquad(hp[16]);
      float4 h3 = bquad(hp[24]);
      acc0 = fma4(acc0, a0.x, h0); acc0 = fma4(acc0, a0.y, h1);
      acc0 = fma4(acc0, a0.z, h2); acc0 = fma4(acc0, a0.w, h3);
      acc1 = fma4(acc1, a1.x, h0); acc1 = fma4(acc1, a1.y, h1);
      acc1 = fma4(acc1, a1.z, h2); acc1 = fma4(acc1, a1.w, h3);
      acc2 = fma4(acc2, a2.x, h0); acc2 = fma4(acc2, a2.y, h1);
      acc2 = fma4(acc2, a2.z, h2); acc2 = fma4(acc2, a2.w, h3);
      acc3 = fma4(acc3, a3.x, h0); acc3 = fma4(acc3, a3.y, h1);
      acc3 = fma4(acc3, a3.z, h2); acc3 = fma4(acc3, a3.w, h3);
    }
    *(float4*)&gbuf[(ng * 4 + 0) * 32 + cg * 4] = acc0;
    *(float4*)&gbuf[(ng * 4 + 1) * 32 + cg * 4] = acc1;
    *(float4*)&gbuf[(ng * 4 + 2) * 32 + cg * 4] = acc2;
    *(float4*)&gbuf[(ng * 4 + 3) * 32 + cg * 4] = acc3;
    __syncthreads();
    // phase B: out[n][o] = bias + sum_{k,c} x_k[n][c] * W[n][k][o][c]
    for (int nn = 0; nn < 8; ++nn) {
      int nl = nl0 + nn * 8, n = chunk * 64 + nl;
      float acc = biasn[n * 32 + o];
      const float4* W4 = (const float4*)(Wn + n * 3072);
#pragma unroll
      for (int c4 = 0; c4 < 8; ++c4) {
        float4 w0 = W4[0 * 256 + o * 8 + c4];
        float4 x0 = bquad(*(const uint2*)&hs[n * 32 + c4 * 4]);
        acc += w0.x * x0.x + w0.y * x0.y + w0.z * x0.z + w0.w * x0.w;
        float4 w1 = W4[1 * 256 + o * 8 + c4];
        float4 x1 = *(const float4*)&g1[nl * 32 + c4 * 4];
        acc += w1.x * x1.x + w1.y * x1.y + w1.z * x1.z + w1.w * x1.w;
        float4 w2 = W4[2 * 256 + o * 8 + c4];
        float4 x2 = *(const float4*)&g2[nl * 32 + c4 * 4];
        acc += w2.x * x2.x + w2.y * x2.y + w2.z * x2.z + w2.w * x2.w;
      }
      hout[(bt * 512 + n) * 32 + o] = acc;
    }
    __syncthreads();
  }
}

// ---------------- TCN (all 3 dilation blocks fused) ----------------
// One block per bn. in: hA [bt][n][d], out: hB [bn][t][d]
__global__ void __launch_bounds__(256) tcn_kernel(
    const float* __restrict__ hin, float* __restrict__ hout,
    const float* __restrict__ w1g, const float* __restrict__ b1g,
    const float* __restrict__ w2g, const float* __restrict__ b2g) {
  const int TP = 132;
  __shared__ float ybuf[32 * 132];
  __shared__ float obuf[32 * 132];
  __shared__ float wbuf[3072];
  __shared__ float bbuf[32];
  int bn = blockIdx.x, tid = threadIdx.x;
  int b = bn >> 9, n = bn & 511;
  for (int idx = tid; idx < 4096; idx += 256) {
    int c = idx & 31, t = idx >> 5;
    ybuf[c * TP + t] = hin[((b * 128 + t) * 512 + n) * 32 + c];
  }
  const int og = tid & 7, tg = tid >> 3;
  const int o0 = og * 4, t0 = tg * 4;
  for (int blk = 0; blk < 3; ++blk) {
    int dil = 1 << blk;
    __syncthreads();
    for (int idx = tid; idx < 3072; idx += 256) wbuf[idx] = w1g[blk * 3072 + idx];
    if (tid < 32) bbuf[tid] = b1g[blk * 32 + tid];
    __syncthreads();
    float acc[4][4];
#pragma unroll
    for (int oo = 0; oo < 4; ++oo)
#pragma unroll
      for (int dt = 0; dt < 4; ++dt) acc[oo][dt] = bbuf[o0 + oo];
    for (int c = 0; c < 32; ++c) {
      const float* yr = &ybuf[c * TP];
      float yv[4][3];
#pragma unroll
      for (int dt = 0; dt < 4; ++dt)
#pragma unroll
        for (int kk = 0; kk < 3; ++kk) {
          int tt = t0 + dt - (2 - kk) * dil;
          yv[dt][kk] = (tt >= 0) ? yr[tt] : 0.f;
        }
      const float* wr = &wbuf[(o0 * 32 + c) * 3];
#pragma unroll
      for (int oo = 0; oo < 4; ++oo) {
        float w0 = wr[oo * 96 + 0], w1 = wr[oo * 96 + 1], w2 = wr[oo * 96 + 2];
#pragma unroll
        for (int dt = 0; dt < 4; ++dt)
          acc[oo][dt] += w0 * yv[dt][0] + w1 * yv[dt][1] + w2 * yv[dt][2];
      }
    }
#pragma unroll
    for (int oo = 0; oo < 4; ++oo)
#pragma unroll
      for (int dt = 0; dt < 4; ++dt)
        obuf[(o0 + oo) * TP + t0 + dt] = fmaxf(acc[oo][dt], 0.f);
    __syncthreads();
    for (int idx = tid; idx < 3072; idx += 256) wbuf[idx] = w2g[blk * 3072 + idx];
    if (tid < 32) bbuf[tid] = b2g[blk * 32 + tid];
    __syncthreads();
#pragma unroll
    for (int oo = 0; oo < 4; ++oo)
#pragma unroll
      for (int dt = 0; dt < 4; ++dt) acc[oo][dt] = bbuf[o0 + oo];
    for (int c = 0; c < 32; ++c) {
      const float* yr = &obuf[c * TP];
      float yv[4][3];
#pragma unroll
      for (int dt = 0; dt < 4; ++dt)
#pragma unroll
        for (int kk = 0; kk < 3; ++kk) {
          int tt = t0 + dt - (2 - kk) * dil;
          yv[dt][kk] = (tt >= 0) ? yr[tt] : 0.f;
        }
      const float* wr = &wbuf[(o0 * 32 + c) * 3];
#pragma unroll
      for (int oo = 0; oo < 4; ++oo) {
        float w0 = wr[oo * 96 + 0], w1 = wr[oo * 96 + 1], w2 = wr[oo * 96 + 2];
#pragma unroll
        for (int dt = 0; dt < 4; ++dt)
          acc[oo][dt] += w0 * yv[dt][0] + w1 * yv[dt][1] + w2 * yv[dt][2];
      }
    }
#pragma unroll
    for (int oo = 0; oo < 4; ++oo)
#pragma unroll
      for (int dt = 0; dt < 4; ++dt) {
        float o2 = fmaxf(acc[oo][dt], 0.f);
        float y = ybuf[(o0 + oo) * TP + t0 + dt];
        ybuf[(o0 + oo) * TP + t0 + dt] = fmaxf(o2 + y, 0.f);
      }
  }
  __syncthreads();
  for (int idx = tid; idx < 4096; idx += 256) {
    int d = idx & 31, t = idx >> 5;
    hout[(bn * 128 + t) * 32 + d] = ybuf[d * TP + t];
  }
}

// ---------------- attention (both layers fused) ----------------
__global__ void __launch_bounds__(256) attn_kernel(
    const float* __restrict__ hin,  // [bn][t][d]
    float* __restrict__ outp,       // (B,T,N,D) fp32
    const float* __restrict__ wqg, const float* __restrict__ wkg,
    const float* __restrict__ wvg, const float* __restrict__ wog,
    const float* __restrict__ gg, const float* __restrict__ bgb) {
  const int PB = 34, PA = 33;
  __shared__ unsigned short hsb[128 * 34];
  __shared__ unsigned short kb2[128 * 34];
  __shared__ unsigned short vb2[128 * 34];
  __shared__ float ab[128 * 33];
  __shared__ float sb[16 * 128];
  __shared__ float qb[16 * 16];
  int bn = blockIdx.x, tid = threadIdx.x;
  int b = bn >> 9, n = bn & 511;
  for (int idx = tid; idx < 4096; idx += 256) {
    int d = idx & 31, t = idx >> 5;
    hsb[t * PB + d] = f2b(hin[(bn * 128 + t) * 32 + d]);
  }
  __syncthreads();
  const int d = tid & 31, trow = tid >> 5;
  const int r16 = tid >> 4, j16 = tid & 15;
  for (int L = 0; L < 2; ++L) {
    const float* wq = wqg + L * 1024;
    const float* wk = wkg + L * 1024;
    const float* wv = wvg + L * 1024;
    const float* wo = wog + L * 1024;
    // K, V projections (weight columns preloaded to regs)
    {
      float wkc[32], wvc[32];
#pragma unroll
      for (int c = 0; c < 32; ++c) {
        wkc[c] = wk[c * 32 + d];
        wvc[c] = wv[c * 32 + d];
      }
      for (int tt = 0; tt < 16; ++tt) {
        int t = trow * 16 + tt;
        const unsigned int* hr = (const unsigned int*)&hsb[t * PB];
        float aK = 0.f, aV = 0.f;
#pragma unroll
        for (int c2 = 0; c2 < 16; ++c2) {
          float2 hv = bpair(hr[c2]);
          aK += hv.x * wkc[2 * c2] + hv.y * wkc[2 * c2 + 1];
          aV += hv.x * wvc[2 * c2] + hv.y * wvc[2 * c2 + 1];
        }
        kb2[t * PB + d] = f2b(aK);
        vb2[t * PB + d] = f2b(aV);
      }
    }
    __syncthreads();
    for (int hh = 0; hh < 2; ++hh) {
      for (int qc = 0; qc < 8; ++qc) {
        {  // Q chunk (16 rows x 16 head-dims), scale folded in
          int t = qc * 16 + r16;
          const unsigned int* hr = (const unsigned int*)&hsb[t * PB];
          float a = 0.f;
#pragma unroll
          for (int c2 = 0; c2 < 16; ++c2) {
            float2 hv = bpair(hr[c2]);
            a += hv.x * wq[(2 * c2) * 32 + hh * 16 + j16];
            a += hv.y * wq[(2 * c2 + 1) * 32 + hh * 16 + j16];
          }
          qb[r16 * 16 + j16] = a * 0.25f;
        }
        __syncthreads();
#pragma unroll
        for (int i = 0; i < 8; ++i) {  // scores 16x128
          int task = i * 256 + tid;
          int r = task >> 7, kt = task & 127;
          const unsigned int* kr = (const unsigned int*)&kb2[kt * PB + hh * 16];
          float a = 0.f;
#pragma unroll
          for (int j2 = 0; j2 < 8; ++j2) {
            float2 kv = bpair(kr[j2]);
            a += qb[r * 16 + 2 * j2] * kv.x + qb[r * 16 + 2 * j2 + 1] * kv.y;
          }
          sb[r * 128 + kt] = a;
        }
        __syncthreads();
        {  // softmax over 128 per row; 16 lanes per row, 8 elems each
          float ev[8];
          float mx = -1e30f;
#pragma unroll
          for (int ii = 0; ii < 8; ++ii) mx = fmaxf(mx, sb[r16 * 128 + j16 + ii * 16]);
          for (int mask = 1; mask < 16; mask <<= 1) mx = fmaxf(mx, __shfl_xor(mx, mask));
          float sum = 0.f;
#pragma unroll
          for (int ii = 0; ii < 8; ++ii) {
            float e = __expf(sb[r16 * 128 + j16 + ii * 16] - mx);
            ev[ii] = e; sum += e;
          }
          for (int mask = 1; mask < 16; mask <<= 1) sum += __shfl_xor(sum, mask);
          float inv = 1.f / sum;
#pragma unroll
          for (int ii = 0; ii < 8; ++ii) sb[r16 * 128 + j16 + ii * 16] = ev[ii] * inv;
        }
        __syncthreads();
        {  // P @ V
          int t = qc * 16 + r16;
          float a = 0.f;
          for (int kt = 0; kt < 128; ++kt)
            a += sb[r16 * 128 + kt] * b2f(vb2[kt * PB + hh * 16 + j16]);
          ab[t * PA + hh * 16 + j16] = a;
        }
        __syncthreads();
      }
    }
    // output proj + residual + layernorm
    {
      float woc[32];
#pragma unroll
      for (int c = 0; c < 32; ++c) woc[c] = wo[c * 32 + d];
      float gam = gg[L * 32 + d], bet = bgb[L * 32 + d];
      for (int tt = 0; tt < 16; ++tt) {
        int t = trow + tt * 8;  // lanes 0..31 share t -> shfl-32 LN reduce
        float ho = 0.f;
#pragma unroll
        for (int c = 0; c < 32; ++c) ho += ab[t * PA + c] * woc[c];
        float r = b2f(hsb[t * PB + d]) + ho;
        float sm = r;
        for (int mask = 1; mask < 32; mask <<= 1) sm += __shfl_xor(sm, mask);
        float mu = sm * 0.03125f;
        float dx = r - mu;
        float sq = dx * dx;
        for (int mask = 1; mask < 32; mask <<= 1) sq += __shfl_xor(sq, mask);
        float var = sq * 0.03125f;
        float yv = dx * rsqrtf(var + 1e-5f) * gam + bet;
        if (L == 0)
          hsb[t * PB + d] = f2b(yv);
        else
          outp[((b * 128 + t) * 512 + n) * 32 + d] = yv;
      }
    }
    __syncthreads();
  }
}

extern "C" void kernel_launch(void* const* d_in, const int* in_sizes, int n_in,
                              void* d_out, int out_size, void* d_ws, size_t ws_size,
                              hipStream_t stream) {
  const float* x    = (const float*)d_in[0];
  // d_in[1] init_state: unused
  const float* emb  = (const float*)d_in[2];
  const float* adj  = (const float*)d_in[3];
  const float* gw   = (const float*)d_in[4];
  const float* gb   = (const float*)d_in[5];
  const float* tw1  = (const float*)d_in[6];
  const float* tb1  = (const float*)d_in[7];
  const float* tw2  = (const float*)d_in[8];
  const float* tb2  = (const float*)d_in[9];
  const float* wq   = (const float*)d_in[10];
  const float* wk   = (const float*)d_in[11];
  const float* wv   = (const float*)d_in[12];
  const float* wo   = (const float*)d_in[13];
  const float* tg   = (const float*)d_in[14];
  const float* tbb  = (const float*)d_in[15];
  float* outp = (float*)d_out;

  float* ws    = (float*)d_ws;
  float* s2f   = ws;                   // 262144
  float* Wn    = s2f + 262144;         // 4718592
  float* biasn = Wn + 4718592;         // 49152
  float* hA    = biasn + 49152;        // 8388608
  float* hB    = hA + 8388608;         // 8388608   (~87 MB total)

  prep_adj_kernel<<<dim3(512), dim3(256), 0, stream>>>(adj, s2f);
  prep_w_kernel<<<dim3(1536), dim3(256), 0, stream>>>(emb, gw, gb, Wn, biasn);
  gcn_kernel<<<dim3(512), dim3(256), 0, stream>>>(x, hA, Wn, biasn, adj, s2f);
  gcn_kernel<<<dim3(512), dim3(256), 0, stream>>>(hA, hB, Wn + 1572864, biasn + 16384, adj, s2f);
  gcn_kernel<<<dim3(512), dim3(256), 0, stream>>>(hB, hA, Wn + 3145728, biasn + 32768, adj, s2f);
  tcn_kernel<<<dim3(2048), dim3(256), 0, stream>>>(hA, hB, tw1, tb1, tw2, tb2);
  attn_kernel<<<dim3(2048), dim3(256), 0, stream>>>(hB, outp, wq, wk, wv, wo, tg, tbb);
}

// Round 3
// 1934.185 us; speedup vs baseline: 1.6853x; 1.6853x over previous
//
#include <hip/hip_runtime.h>

// B=4, T=128, N=512, D=32, CHEB_K=3, EMB=10, HEADS=2, TA_LAYERS=2, GCN_NUM=3,
// TCN_BLOCKS=3, KSIZE=3.  Inputs/outputs fp32; internal bf16 + MFMA phase A.

typedef __attribute__((ext_vector_type(8))) short short8;
typedef __attribute__((ext_vector_type(4))) float float4v;

__device__ __forceinline__ unsigned short f2b(float f) {
  unsigned int x = __float_as_uint(f);
  unsigned int r = (x + 0x7fffu + ((x >> 16) & 1u)) >> 16;
  return (unsigned short)r;
}
__device__ __forceinline__ float b2f(unsigned short u) {
  return __uint_as_float(((unsigned int)u) << 16);
}
__device__ __forceinline__ float2 bpair(unsigned int p) {
  float2 r;
  r.x = __uint_as_float(p << 16);
  r.y = __uint_as_float(p & 0xffff0000u);
  return r;
}

// ---------------- prep: supports in bf16 ----------------
// Sb[n][m] = adj[n][m];  Sb[512+n][m] = 2*(adj@adj)[n][m] - I
__global__ void __launch_bounds__(256) prep_supports(
    const float* __restrict__ adj, unsigned short* __restrict__ Sb) {
  __shared__ float arow[512];
  int n = blockIdx.x, tid = threadIdx.x;
  for (int m = tid; m < 512; m += 256) {
    float v = adj[n * 512 + m];
    arow[m] = v;
    Sb[n * 512 + m] = f2b(v);
  }
  __syncthreads();
  for (int m = tid; m < 512; m += 256) {
    float acc = 0.f;
    for (int p = 0; p < 512; ++p) acc += arow[p] * adj[p * 512 + m];
    Sb[(512 + n) * 512 + m] = f2b(2.f * acc - (m == n ? 1.f : 0.f));
  }
}

// ---------------- prep: per-node GCN weights ----------------
// Wn[i][n][k][c][o] = sum_e E[n,e]*gw[i,e,k,c,o]  (same inner layout as gw)
__global__ void __launch_bounds__(256) prep_w_kernel(
    const float* __restrict__ emb, const float* __restrict__ gw,
    const float* __restrict__ gb,
    float* __restrict__ Wn, float* __restrict__ biasn) {
  int bid = blockIdx.x;  // 0..1535
  int i = bid >> 9, n = bid & 511, tid = threadIdx.x;
  float ev[10];
#pragma unroll
  for (int e = 0; e < 10; ++e) ev[e] = emb[n * 10 + e];
  for (int idx = tid; idx < 3072; idx += 256) {
    float acc = 0.f;
#pragma unroll
    for (int e = 0; e < 10; ++e) acc += ev[e] * gw[(i * 10 + e) * 3072 + idx];
    Wn[(i * 512 + n) * 3072 + idx] = acc;
  }
  if (tid < 32) {
    float acc = 0.f;
#pragma unroll
    for (int e = 0; e < 10; ++e) acc += ev[e] * gb[(i * 10 + e) * 32 + tid];
    biasn[(i * 512 + n) * 32 + tid] = acc;
  }
}

// ---------------- x -> H8 swizzled bf16 ----------------
// H8[n>>3][j=bt*32+c][n&7] = bf16(x[bt][n][c])
__global__ void __launch_bounds__(256) conv_x(
    const float* __restrict__ x, unsigned short* __restrict__ H8) {
  int bid = blockIdx.x;  // 512 = nblk(64) x btc(8)
  int nblk = bid >> 3, btc = bid & 7;
  int tid = threadIdx.x, s = tid >> 5, c = tid & 31;
  for (int bti = 0; bti < 64; ++bti) {
    int bt = btc * 64 + bti;
    float v = x[bt * 16384 + nblk * 256 + tid];
    H8[nblk * 131072 + (bt * 32 + c) * 8 + s] = f2b(v);
  }
}

// ---------------- GCN phase A: G = S @ H  (MFMA) ----------------
// Sb: [1024][512] bf16 row-major.  H8: swizzled.  G: [1024][16384] fp32.
#define AST 40
__global__ void __launch_bounds__(256) gcn_phaseA(
    const unsigned short* __restrict__ Sb,
    const unsigned short* __restrict__ H8,
    float* __restrict__ G) {
  __shared__ unsigned short As[128 * AST];
  __shared__ unsigned short Bs[4096];
  int bid = blockIdx.x;           // 1024 = jt(128) x mt(8), m-major adjacent
  int mt = bid & 7, jt = bid >> 3;
  int m0 = mt * 128, j0 = jt * 128;
  int tid = threadIdx.x;
  int wave = tid >> 6, lane = tid & 63;
  int wm = wave >> 1, wj = wave & 1;
  int l15 = lane & 15, quad = lane >> 4;
  float4v acc[4][4];
#pragma unroll
  for (int a = 0; a < 4; ++a)
#pragma unroll
    for (int b = 0; b < 4; ++b) acc[a][b] = (float4v)0.f;
  for (int nc = 0; nc < 512; nc += 32) {
    // stage A-tile (128 x 32 bf16)
#pragma unroll
    for (int p = 0; p < 2; ++p) {
      int q = tid + p * 256;
      int m = q >> 2, seg = q & 3;
      *(uint4*)&As[m * AST + seg * 8] =
          *(const uint4*)&Sb[(m0 + m) * 512 + nc + seg * 8];
    }
    // stage B-tile (32k x 128j) — already fragment-swizzled in global
    const unsigned short* hb = H8 + (nc >> 3) * 131072 + j0 * 8;
#pragma unroll
    for (int p = 0; p < 2; ++p) {
      int q = tid + p * 256;
      int nb = q >> 7, rem = q & 127;
      *(uint4*)&Bs[nb * 1024 + rem * 8] =
          *(const uint4*)&hb[nb * 131072 + rem * 8];
    }
    __syncthreads();
    short8 af[4], bfr[4];
#pragma unroll
    for (int mi = 0; mi < 4; ++mi)
      af[mi] = *(const short8*)&As[(wm * 64 + mi * 16 + l15) * AST + quad * 8];
#pragma unroll
    for (int ji = 0; ji < 4; ++ji)
      bfr[ji] = *(const short8*)&Bs[quad * 1024 + (wj * 64 + ji * 16 + l15) * 8];
#pragma unroll
    for (int mi = 0; mi < 4; ++mi)
#pragma unroll
      for (int ji = 0; ji < 4; ++ji)
        acc[mi][ji] = __builtin_amdgcn_mfma_f32_16x16x32_bf16(
            af[mi], bfr[ji], acc[mi][ji], 0, 0, 0);
    __syncthreads();
  }
  // epilogue: C/D layout col=lane&15, row=quad*4+reg
#pragma unroll
  for (int mi = 0; mi < 4; ++mi)
#pragma unroll
    for (int ji = 0; ji < 4; ++ji) {
      int j = j0 + wj * 64 + ji * 16 + l15;
#pragma unroll
      for (int r = 0; r < 4; ++r) {
        int m = m0 + wm * 64 + mi * 16 + quad * 4 + r;
        G[m * 16384 + j] = acc[mi][ji][r];
      }
    }
}

// ---------------- GCN phase B: per-node weight apply (VALU fp32) --------
// out[n][bt][o] = bias[n][o] + sum_{k,c} X_k[n][bt][c]*W[n][k][c][o]
#define XST 132
__global__ void __launch_bounds__(256) gcn_phaseB(
    const unsigned short* __restrict__ H8in, const float* __restrict__ G,
    const float* __restrict__ Wn, const float* __restrict__ biasn,
    unsigned short* __restrict__ H8out) {
  __shared__ float Xl[3][32 * XST];
  __shared__ float Wl[3072];
  int bid = blockIdx.x;  // 256 = nblk(64) x btc(4)
  int nblk = bid >> 2, btc = bid & 3;
  int bt0 = btc * 128;
  int tid = threadIdx.x;
  int o4 = (tid & 7) * 4, btq = tid >> 3;
  for (int ni = 0; ni < 8; ++ni) {
    int n = nblk * 8 + ni;
    for (int e = tid; e < 3072; e += 256) Wl[e] = Wn[n * 3072 + e];
#pragma unroll
    for (int p = 0; p < 4; ++p) {
      int idx = tid + p * 256;  // 1024: bt(128) x c4(8)
      int bt = idx >> 3, c4 = idx & 7;
      int jb = (bt0 + bt) * 32 + c4 * 4;
#pragma unroll
      for (int u = 0; u < 4; ++u)
        Xl[0][(c4 * 4 + u) * XST + bt] =
            b2f(H8in[nblk * 131072 + (jb + u) * 8 + ni]);
      float4 g1 = *(const float4*)&G[n * 16384 + jb];
      float4 g2 = *(const float4*)&G[(512 + n) * 16384 + jb];
      Xl[1][(c4 * 4 + 0) * XST + bt] = g1.x;
      Xl[1][(c4 * 4 + 1) * XST + bt] = g1.y;
      Xl[1][(c4 * 4 + 2) * XST + bt] = g1.z;
      Xl[1][(c4 * 4 + 3) * XST + bt] = g1.w;
      Xl[2][(c4 * 4 + 0) * XST + bt] = g2.x;
      Xl[2][(c4 * 4 + 1) * XST + bt] = g2.y;
      Xl[2][(c4 * 4 + 2) * XST + bt] = g2.z;
      Xl[2][(c4 * 4 + 3) * XST + bt] = g2.w;
    }
    __syncthreads();
    float acc[4][4];
#pragma unroll
    for (int a = 0; a < 4; ++a)
#pragma unroll
      for (int b = 0; b < 4; ++b) acc[a][b] = 0.f;
    for (int k = 0; k < 3; ++k)
#pragma unroll 4
      for (int c = 0; c < 32; ++c) {
        float4 w = *(const float4*)&Wl[(k * 32 + c) * 32 + o4];
        float4 xv = *(const float4*)&Xl[k][c * XST + btq * 4];
        float xx[4] = {xv.x, xv.y, xv.z, xv.w};
        float ww[4] = {w.x, w.y, w.z, w.w};
#pragma unroll
        for (int bi = 0; bi < 4; ++bi)
#pragma unroll
          for (int oi = 0; oi < 4; ++oi) acc[bi][oi] += xx[bi] * ww[oi];
      }
    float4 bs = *(const float4*)&biasn[n * 32 + o4];
    float bb[4] = {bs.x, bs.y, bs.z, bs.w};
#pragma unroll
    for (int bi = 0; bi < 4; ++bi) {
      int bt = bt0 + btq * 4 + bi;
#pragma unroll
      for (int oi = 0; oi < 4; ++oi)
        H8out[nblk * 131072 + (bt * 32 + o4 + oi) * 8 + ni] =
            f2b(acc[bi][oi] + bb[oi]);
    }
    __syncthreads();
  }
}

// ---------------- TCN (3 dilated blocks fused) ----------------
// in: H8 swizzled bf16; out: yplain bf16 [n][bt*32+d]
__global__ void __launch_bounds__(256) tcn_kernel(
    const unsigned short* __restrict__ H8, unsigned short* __restrict__ yout,
    const float* __restrict__ w1g, const float* __restrict__ b1g,
    const float* __restrict__ w2g, const float* __restrict__ b2g) {
  const int TP = 132;
  __shared__ float ybuf[32 * 132];
  __shared__ float obuf[32 * 132];
  __shared__ float wbuf[3072];
  __shared__ float bbuf[32];
  int g = blockIdx.x;  // swizzle: same-nblk blocks on same XCD
  int n = (g & 7) * 64 + ((g >> 3) & 63);
  int b = g >> 9;
  int tid = threadIdx.x;
  const unsigned short* hb = H8 + (n >> 3) * 131072 + (n & 7);
  for (int idx = tid; idx < 4096; idx += 256) {
    int c = idx & 31, t = idx >> 5;
    ybuf[c * TP + t] = b2f(hb[(b * 4096 + idx) * 8]);
  }
  const int og = tid & 7, tg = tid >> 3;
  const int o0 = og * 4, t0 = tg * 4;
  for (int blk = 0; blk < 3; ++blk) {
    int dil = 1 << blk;
    __syncthreads();
    for (int idx = tid; idx < 3072; idx += 256) wbuf[idx] = w1g[blk * 3072 + idx];
    if (tid < 32) bbuf[tid] = b1g[blk * 32 + tid];
    __syncthreads();
    float acc[4][4];
#pragma unroll
    for (int oo = 0; oo < 4; ++oo)
#pragma unroll
      for (int dt = 0; dt < 4; ++dt) acc[oo][dt] = bbuf[o0 + oo];
    for (int c = 0; c < 32; ++c) {
      const float* yr = &ybuf[c * TP];
      float yv[4][3];
#pragma unroll
      for (int dt = 0; dt < 4; ++dt)
#pragma unroll
        for (int kk = 0; kk < 3; ++kk) {
          int tt = t0 + dt - (2 - kk) * dil;
          yv[dt][kk] = (tt >= 0) ? yr[tt] : 0.f;
        }
      const float* wr = &wbuf[(o0 * 32 + c) * 3];
#pragma unroll
      for (int oo = 0; oo < 4; ++oo) {
        float w0 = wr[oo * 96 + 0], w1 = wr[oo * 96 + 1], w2 = wr[oo * 96 + 2];
#pragma unroll
        for (int dt = 0; dt < 4; ++dt)
          acc[oo][dt] += w0 * yv[dt][0] + w1 * yv[dt][1] + w2 * yv[dt][2];
      }
    }
#pragma unroll
    for (int oo = 0; oo < 4; ++oo)
#pragma unroll
      for (int dt = 0; dt < 4; ++dt)
        obuf[(o0 + oo) * TP + t0 + dt] = fmaxf(acc[oo][dt], 0.f);
    __syncthreads();
    for (int idx = tid; idx < 3072; idx += 256) wbuf[idx] = w2g[blk * 3072 + idx];
    if (tid < 32) bbuf[tid] = b2g[blk * 32 + tid];
    __syncthreads();
#pragma unroll
    for (int oo = 0; oo < 4; ++oo)
#pragma unroll
      for (int dt = 0; dt < 4; ++dt) acc[oo][dt] = bbuf[o0 + oo];
    for (int c = 0; c < 32; ++c) {
      const float* yr = &obuf[c * TP];
      float yv[4][3];
#pragma unroll
      for (int dt = 0; dt < 4; ++dt)
#pragma unroll
        for (int kk = 0; kk < 3; ++kk) {
          int tt = t0 + dt - (2 - kk) * dil;
          yv[dt][kk] = (tt >= 0) ? yr[tt] : 0.f;
        }
      const float* wr = &wbuf[(o0 * 32 + c) * 3];
#pragma unroll
      for (int oo = 0; oo < 4; ++oo) {
        float w0 = wr[oo * 96 + 0], w1 = wr[oo * 96 + 1], w2 = wr[oo * 96 + 2];
#pragma unroll
        for (int dt = 0; dt < 4; ++dt)
          acc[oo][dt] += w0 * yv[dt][0] + w1 * yv[dt][1] + w2 * yv[dt][2];
      }
    }
#pragma unroll
    for (int oo = 0; oo < 4; ++oo)
#pragma unroll
      for (int dt = 0; dt < 4; ++dt) {
        float o2 = fmaxf(acc[oo][dt], 0.f);
        float y = ybuf[(o0 + oo) * TP + t0 + dt];
        ybuf[(o0 + oo) * TP + t0 + dt] = fmaxf(o2 + y, 0.f);
      }
  }
  __syncthreads();
  for (int idx = tid; idx < 4096; idx += 256) {
    int d = idx & 31, t = idx >> 5;
    yout[n * 16384 + b * 4096 + idx] = f2b(ybuf[d * TP + t]);
  }
}

// ---------------- attention (both layers fused) ----------------
__global__ void __launch_bounds__(256) attn_kernel(
    const unsigned short* __restrict__ yin,  // bf16 [n][bt*32+d]
    float* __restrict__ outp,
    const float* __restrict__ wqg, const float* __restrict__ wkg,
    const float* __restrict__ wvg, const float* __restrict__ wog,
    const float* __restrict__ gg, const float* __restrict__ bgb) {
  const int PB = 34;
  __shared__ unsigned short hsb[128 * 34];
  __shared__ unsigned short qfull[128 * 34];
  __shared__ unsigned short kb2[128 * 34];
  __shared__ unsigned short vb2[128 * 34];
  __shared__ unsigned short ab[128 * 34];
  __shared__ float sbT[128 * 17];
  int bn = blockIdx.x, tid = threadIdx.x;
  int b = bn >> 9, n = bn & 511;
  const unsigned short* src = yin + n * 16384 + b * 4096;
  for (int idx = tid; idx < 4096; idx += 256) {
    int d = idx & 31, t = idx >> 5;
    hsb[t * PB + d] = src[idx];
  }
  __syncthreads();
  const int d = tid & 31, trow = tid >> 5;
  const int r16 = tid >> 4, j16 = tid & 15;
  for (int L = 0; L < 2; ++L) {
    const float* wq = wqg + L * 1024;
    const float* wk = wkg + L * 1024;
    const float* wv = wvg + L * 1024;
    const float* wo = wog + L * 1024;
    {  // K,V projections, then Q (register reuse across passes)
      float wa[32], wb[32];
#pragma unroll
      for (int c = 0; c < 32; ++c) {
        wa[c] = wk[c * 32 + d];
        wb[c] = wv[c * 32 + d];
      }
      for (int tt = 0; tt < 16; ++tt) {
        int t = trow * 16 + tt;
        const unsigned int* hr = (const unsigned int*)&hsb[t * PB];
        float aK = 0.f, aV = 0.f;
#pragma unroll
        for (int c2 = 0; c2 < 16; ++c2) {
          float2 hv = bpair(hr[c2]);
          aK += hv.x * wa[2 * c2] + hv.y * wa[2 * c2 + 1];
          aV += hv.x * wb[2 * c2] + hv.y * wb[2 * c2 + 1];
        }
        kb2[t * PB + d] = f2b(aK);
        vb2[t * PB + d] = f2b(aV);
      }
#pragma unroll
      for (int c = 0; c < 32; ++c) wa[c] = wq[c * 32 + d];
      for (int tt = 0; tt < 16; ++tt) {
        int t = trow * 16 + tt;
        const unsigned int* hr = (const unsigned int*)&hsb[t * PB];
        float aQ = 0.f;
#pragma unroll
        for (int c2 = 0; c2 < 16; ++c2) {
          float2 hv = bpair(hr[c2]);
          aQ += hv.x * wa[2 * c2] + hv.y * wa[2 * c2 + 1];
        }
        qfull[t * PB + d] = f2b(aQ * 0.25f);  // 1/sqrt(16) folded in
      }
    }
    __syncthreads();
    for (int hh = 0; hh < 2; ++hh) {
      for (int qc = 0; qc < 8; ++qc) {
#pragma unroll
        for (int i = 0; i < 8; ++i) {  // scores 16x128 -> sbT[kt][r]
          int task = i * 256 + tid;
          int r = task >> 7, kt = task & 127;
          const unsigned int* qr =
              (const unsigned int*)&qfull[(qc * 16 + r) * PB + hh * 16];
          const unsigned int* kr =
              (const unsigned int*)&kb2[kt * PB + hh * 16];
          float a = 0.f;
#pragma unroll
          for (int j2 = 0; j2 < 8; ++j2) {
            float2 qv = bpair(qr[j2]);
            float2 kv = bpair(kr[j2]);
            a += qv.x * kv.x + qv.y * kv.y;
          }
          sbT[kt * 17 + r] = a;
        }
        __syncthreads();
        {  // softmax over 128 per row
          float ev[8];
          float mx = -1e30f;
#pragma unroll
          for (int ii = 0; ii < 8; ++ii)
            mx = fmaxf(mx, sbT[(j16 + ii * 16) * 17 + r16]);
          for (int mask = 1; mask < 16; mask <<= 1)
            mx = fmaxf(mx, __shfl_xor(mx, mask));
          float sum = 0.f;
#pragma unroll
          for (int ii = 0; ii < 8; ++ii) {
            float e = __expf(sbT[(j16 + ii * 16) * 17 + r16] - mx);
            ev[ii] = e; sum += e;
          }
          for (int mask = 1; mask < 16; mask <<= 1) sum += __shfl_xor(sum, mask);
          float inv = 1.f / sum;
#pragma unroll
          for (int ii = 0; ii < 8; ++ii)
            sbT[(j16 + ii * 16) * 17 + r16] = ev[ii] * inv;
        }
        __syncthreads();
        {  // P @ V (sbT reads now conflict-free)
          int t = qc * 16 + r16;
          float a = 0.f;
          for (int kt = 0; kt < 128; ++kt)
            a += sbT[kt * 17 + r16] * b2f(vb2[kt * PB + hh * 16 + j16]);
          ab[t * PB + hh * 16 + j16] = f2b(a);
        }
        __syncthreads();
      }
    }
    {  // output proj + residual + layernorm
      float woc[32];
#pragma unroll
      for (int c = 0; c < 32; ++c) woc[c] = wo[c * 32 + d];
      float gam = gg[L * 32 + d], bet = bgb[L * 32 + d];
      for (int tt = 0; tt < 16; ++tt) {
        int t = trow + tt * 8;
        float ho = 0.f;
#pragma unroll
        for (int c = 0; c < 32; ++c) ho += b2f(ab[t * PB + c]) * woc[c];
        float r = b2f(hsb[t * PB + d]) + ho;
        float sm = r;
        for (int mask = 1; mask < 32; mask <<= 1) sm += __shfl_xor(sm, mask);
        float mu = sm * 0.03125f;
        float dx = r - mu;
        float sq = dx * dx;
        for (int mask = 1; mask < 32; mask <<= 1) sq += __shfl_xor(sq, mask);
        float var = sq * 0.03125f;
        float yv = dx * rsqrtf(var + 1e-5f) * gam + bet;
        if (L == 0)
          hsb[t * PB + d] = f2b(yv);
        else
          outp[((b * 128 + t) * 512 + n) * 32 + d] = yv;
      }
    }
    __syncthreads();
  }
}

extern "C" void kernel_launch(void* const* d_in, const int* in_sizes, int n_in,
                              void* d_out, int out_size, void* d_ws, size_t ws_size,
                              hipStream_t stream) {
  const float* x    = (const float*)d_in[0];
  const float* emb  = (const float*)d_in[2];
  const float* adj  = (const float*)d_in[3];
  const float* gw   = (const float*)d_in[4];
  const float* gb   = (const float*)d_in[5];
  const float* tw1  = (const float*)d_in[6];
  const float* tb1  = (const float*)d_in[7];
  const float* tw2  = (const float*)d_in[8];
  const float* tb2  = (const float*)d_in[9];
  const float* wq   = (const float*)d_in[10];
  const float* wk   = (const float*)d_in[11];
  const float* wv   = (const float*)d_in[12];
  const float* wo   = (const float*)d_in[13];
  const float* tg   = (const float*)d_in[14];
  const float* tbb  = (const float*)d_in[15];
  float* outp = (float*)d_out;

  char* p = (char*)d_ws;
  unsigned short* Sb = (unsigned short*)p;  p += 1048576;
  float* Wn          = (float*)p;           p += 18874368;
  float* biasn       = (float*)p;           p += 196608;
  float* G           = (float*)p;           p += 67108864;
  unsigned short* H8a = (unsigned short*)p; p += 16777216;
  unsigned short* H8b = (unsigned short*)p; p += 16777216;
  unsigned short* ypl = (unsigned short*)p; p += 16777216;  // ~137.6 MB total

  prep_supports<<<dim3(512), dim3(256), 0, stream>>>(adj, Sb);
  prep_w_kernel<<<dim3(1536), dim3(256), 0, stream>>>(emb, gw, gb, Wn, biasn);
  conv_x<<<dim3(512), dim3(256), 0, stream>>>(x, H8a);

  gcn_phaseA<<<dim3(1024), dim3(256), 0, stream>>>(Sb, H8a, G);
  gcn_phaseB<<<dim3(256), dim3(256), 0, stream>>>(H8a, G, Wn, biasn, H8b);
  gcn_phaseA<<<dim3(1024), dim3(256), 0, stream>>>(Sb, H8b, G);
  gcn_phaseB<<<dim3(256), dim3(256), 0, stream>>>(H8b, G, Wn + 1572864,
                                                  biasn + 16384, H8a);
  gcn_phaseA<<<dim3(1024), dim3(256), 0, stream>>>(Sb, H8a, G);
  gcn_phaseB<<<dim3(256), dim3(256), 0, stream>>>(H8a, G, Wn + 3145728,
                                                  biasn + 32768, H8b);

  tcn_kernel<<<dim3(2048), dim3(256), 0, stream>>>(H8b, ypl, tw1, tb1, tw2, tb2);
  attn_kernel<<<dim3(2048), dim3(256), 0, stream>>>(ypl, outp, wq, wk, wv, wo,
                                                    tg, tbb);
}

// Round 4
// 1247.741 us; speedup vs baseline: 2.6124x; 1.5501x over previous
//
#include <hip/hip_runtime.h>

// B=4, T=128, N=512, D=32, CHEB_K=3, EMB=10, HEADS=2, TA_LAYERS=2, GCN_NUM=3,
// TCN_BLOCKS=3, KSIZE=3.  Inputs/outputs fp32; internal bf16 + MFMA.

typedef __attribute__((ext_vector_type(8))) short short8;
typedef __attribute__((ext_vector_type(4))) short short4v;
typedef __attribute__((ext_vector_type(4))) float float4v;

#define MFMA32(a, b, c) __builtin_amdgcn_mfma_f32_16x16x32_bf16((a), (b), (c), 0, 0, 0)
#if defined(__has_builtin)
#if __has_builtin(__builtin_amdgcn_mfma_f32_16x16x16_bf16)
#define MFMA16(a, b) __builtin_amdgcn_mfma_f32_16x16x16_bf16((a), (b), (float4v)0.f, 0, 0, 0)
#elif __has_builtin(__builtin_amdgcn_mfma_f32_16x16x16bf16_1k)
#define MFMA16(a, b) __builtin_amdgcn_mfma_f32_16x16x16bf16_1k((a), (b), (float4v)0.f, 0, 0, 0)
#endif
#endif
#ifndef MFMA16
#define MFMA16(a, b) __builtin_amdgcn_mfma_f32_16x16x16bf16_1k((a), (b), (float4v)0.f, 0, 0, 0)
#endif

__device__ __forceinline__ unsigned short f2b(float f) {
  unsigned int x = __float_as_uint(f);
  unsigned int r = (x + 0x7fffu + ((x >> 16) & 1u)) >> 16;
  return (unsigned short)r;
}
__device__ __forceinline__ float b2f(unsigned short u) {
  return __uint_as_float(((unsigned int)u) << 16);
}

// ---------------- prep: supports in bf16 ----------------
__global__ void __launch_bounds__(256) prep_supports(
    const float* __restrict__ adj, unsigned short* __restrict__ Sb) {
  __shared__ float arow[512];
  int n = blockIdx.x, tid = threadIdx.x;
  for (int m = tid; m < 512; m += 256) {
    float v = adj[n * 512 + m];
    arow[m] = v;
    Sb[n * 512 + m] = f2b(v);
  }
  __syncthreads();
  for (int m = tid; m < 512; m += 256) {
    float acc = 0.f;
    for (int p = 0; p < 512; ++p) acc += arow[p] * adj[p * 512 + m];
    Sb[(512 + n) * 512 + m] = f2b(2.f * acc - (m == n ? 1.f : 0.f));
  }
}

// ---------------- prep: per-node GCN weights ----------------
__global__ void __launch_bounds__(256) prep_w_kernel(
    const float* __restrict__ emb, const float* __restrict__ gw,
    const float* __restrict__ gb,
    float* __restrict__ Wn, float* __restrict__ biasn) {
  int bid = blockIdx.x;  // 0..1535
  int i = bid >> 9, n = bid & 511, tid = threadIdx.x;
  float ev[10];
#pragma unroll
  for (int e = 0; e < 10; ++e) ev[e] = emb[n * 10 + e];
  for (int idx = tid; idx < 3072; idx += 256) {
    float acc = 0.f;
#pragma unroll
    for (int e = 0; e < 10; ++e) acc += ev[e] * gw[(i * 10 + e) * 3072 + idx];
    Wn[(i * 512 + n) * 3072 + idx] = acc;
  }
  if (tid < 32) {
    float acc = 0.f;
#pragma unroll
    for (int e = 0; e < 10; ++e) acc += ev[e] * gb[(i * 10 + e) * 32 + tid];
    biasn[(i * 512 + n) * 32 + tid] = acc;
  }
}

// ---------------- x -> H8 swizzled bf16 ----------------
__global__ void __launch_bounds__(256) conv_x(
    const float* __restrict__ x, unsigned short* __restrict__ H8) {
  int bid = blockIdx.x;  // 512 = nblk(64) x btc(8)
  int nblk = bid >> 3, btc = bid & 7;
  int tid = threadIdx.x, s = tid >> 5, c = tid & 31;
  for (int bti = 0; bti < 64; ++bti) {
    int bt = btc * 64 + bti;
    float v = x[bt * 16384 + nblk * 256 + tid];
    H8[nblk * 131072 + (bt * 32 + c) * 8 + s] = f2b(v);
  }
}

// ---------------- GCN phase A: G = S @ H  (MFMA) ----------------
#define AST 40
__global__ void __launch_bounds__(256) gcn_phaseA(
    const unsigned short* __restrict__ Sb,
    const unsigned short* __restrict__ H8,
    float* __restrict__ G) {
  __shared__ unsigned short As[128 * AST];
  __shared__ unsigned short Bs[4096];
  int bid = blockIdx.x;  // 1024 = jt(128) x mt(8)
  int mt = bid & 7, jt = bid >> 3;
  int m0 = mt * 128, j0 = jt * 128;
  int tid = threadIdx.x;
  int wave = tid >> 6, lane = tid & 63;
  int wm = wave >> 1, wj = wave & 1;
  int l15 = lane & 15, quad = lane >> 4;
  float4v acc[4][4];
#pragma unroll
  for (int a = 0; a < 4; ++a)
#pragma unroll
    for (int b = 0; b < 4; ++b) acc[a][b] = (float4v)0.f;
  for (int nc = 0; nc < 512; nc += 32) {
#pragma unroll
    for (int p = 0; p < 2; ++p) {
      int q = tid + p * 256;
      int m = q >> 2, seg = q & 3;
      *(uint4*)&As[m * AST + seg * 8] =
          *(const uint4*)&Sb[(m0 + m) * 512 + nc + seg * 8];
    }
    const unsigned short* hb = H8 + (nc >> 3) * 131072 + j0 * 8;
#pragma unroll
    for (int p = 0; p < 2; ++p) {
      int q = tid + p * 256;
      int nb = q >> 7, rem = q & 127;
      *(uint4*)&Bs[nb * 1024 + rem * 8] =
          *(const uint4*)&hb[nb * 131072 + rem * 8];
    }
    __syncthreads();
    short8 af[4], bfr[4];
#pragma unroll
    for (int mi = 0; mi < 4; ++mi)
      af[mi] = *(const short8*)&As[(wm * 64 + mi * 16 + l15) * AST + quad * 8];
#pragma unroll
    for (int ji = 0; ji < 4; ++ji)
      bfr[ji] = *(const short8*)&Bs[quad * 1024 + (wj * 64 + ji * 16 + l15) * 8];
#pragma unroll
    for (int mi = 0; mi < 4; ++mi)
#pragma unroll
      for (int ji = 0; ji < 4; ++ji)
        acc[mi][ji] = MFMA32(af[mi], bfr[ji], acc[mi][ji]);
    __syncthreads();
  }
#pragma unroll
  for (int mi = 0; mi < 4; ++mi)
#pragma unroll
    for (int ji = 0; ji < 4; ++ji) {
      int j = j0 + wj * 64 + ji * 16 + l15;
#pragma unroll
      for (int r = 0; r < 4; ++r) {
        int m = m0 + wm * 64 + mi * 16 + quad * 4 + r;
        G[m * 16384 + j] = acc[mi][ji][r];
      }
    }
}

// ---------------- GCN phase B: per-node weight apply ----------------
#define XST 132
__global__ void __launch_bounds__(256) gcn_phaseB(
    const unsigned short* __restrict__ H8in, const float* __restrict__ G,
    const float* __restrict__ Wn, const float* __restrict__ biasn,
    unsigned short* __restrict__ H8out) {
  __shared__ float Xl[3][32 * XST];
  __shared__ float Wl[3072];
  int bid = blockIdx.x;  // 512 = nblk(64) x btc(4) x nih(2)
  int nih = bid & 1, btc = (bid >> 1) & 3, nblk = bid >> 3;
  int bt0 = btc * 128;
  int tid = threadIdx.x;
  int o4 = (tid & 7) * 4, btq = tid >> 3;
  for (int nii = 0; nii < 4; ++nii) {
    int ni = nih * 4 + nii;
    int n = nblk * 8 + ni;
    for (int e = tid; e < 3072; e += 256) Wl[e] = Wn[n * 3072 + e];
#pragma unroll
    for (int p = 0; p < 4; ++p) {
      int idx = tid + p * 256;  // 1024: bt(128) x c4(8)
      int bt = idx >> 3, c4 = idx & 7;
      int jb = (bt0 + bt) * 32 + c4 * 4;
#pragma unroll
      for (int u = 0; u < 4; ++u)
        Xl[0][(c4 * 4 + u) * XST + bt] =
            b2f(H8in[nblk * 131072 + (jb + u) * 8 + ni]);
      float4 g1 = *(const float4*)&G[n * 16384 + jb];
      float4 g2 = *(const float4*)&G[(512 + n) * 16384 + jb];
      Xl[1][(c4 * 4 + 0) * XST + bt] = g1.x;
      Xl[1][(c4 * 4 + 1) * XST + bt] = g1.y;
      Xl[1][(c4 * 4 + 2) * XST + bt] = g1.z;
      Xl[1][(c4 * 4 + 3) * XST + bt] = g1.w;
      Xl[2][(c4 * 4 + 0) * XST + bt] = g2.x;
      Xl[2][(c4 * 4 + 1) * XST + bt] = g2.y;
      Xl[2][(c4 * 4 + 2) * XST + bt] = g2.z;
      Xl[2][(c4 * 4 + 3) * XST + bt] = g2.w;
    }
    __syncthreads();
    float acc[4][4];
#pragma unroll
    for (int a = 0; a < 4; ++a)
#pragma unroll
      for (int b = 0; b < 4; ++b) acc[a][b] = 0.f;
    for (int k = 0; k < 3; ++k)
#pragma unroll 4
      for (int c = 0; c < 32; ++c) {
        float4 w = *(const float4*)&Wl[(k * 32 + c) * 32 + o4];
        float4 xv = *(const float4*)&Xl[k][c * XST + btq * 4];
        float xx[4] = {xv.x, xv.y, xv.z, xv.w};
        float ww[4] = {w.x, w.y, w.z, w.w};
#pragma unroll
        for (int bi = 0; bi < 4; ++bi)
#pragma unroll
          for (int oi = 0; oi < 4; ++oi) acc[bi][oi] += xx[bi] * ww[oi];
      }
    float4 bs = *(const float4*)&biasn[n * 32 + o4];
    float bb[4] = {bs.x, bs.y, bs.z, bs.w};
#pragma unroll
    for (int bi = 0; bi < 4; ++bi) {
      int bt = bt0 + btq * 4 + bi;
#pragma unroll
      for (int oi = 0; oi < 4; ++oi)
        H8out[nblk * 131072 + (bt * 32 + o4 + oi) * 8 + ni] =
            f2b(acc[bi][oi] + bb[oi]);
    }
    __syncthreads();
  }
}

// ---------------- TCN (3 dilated blocks fused) ----------------
__global__ void __launch_bounds__(256) tcn_kernel(
    const unsigned short* __restrict__ H8, unsigned short* __restrict__ yout,
    const float* __restrict__ w1g, const float* __restrict__ b1g,
    const float* __restrict__ w2g, const float* __restrict__ b2g) {
  const int TP = 132;
  __shared__ float ybuf[32 * 132];
  __shared__ float obuf[32 * 132];
  __shared__ float wbuf[3072];
  __shared__ float bbuf[32];
  int g = blockIdx.x;
  int n = (g & 7) * 64 + ((g >> 3) & 63);
  int b = g >> 9;
  int tid = threadIdx.x;
  const unsigned short* hb = H8 + (n >> 3) * 131072 + (n & 7);
  for (int idx = tid; idx < 4096; idx += 256) {
    int c = idx & 31, t = idx >> 5;
    ybuf[c * TP + t] = b2f(hb[(b * 4096 + idx) * 8]);
  }
  const int og = tid & 7, tg = tid >> 3;
  const int o0 = og * 4, t0 = tg * 4;
  for (int blk = 0; blk < 3; ++blk) {
    int dil = 1 << blk;
    __syncthreads();
    for (int idx = tid; idx < 3072; idx += 256) wbuf[idx] = w1g[blk * 3072 + idx];
    if (tid < 32) bbuf[tid] = b1g[blk * 32 + tid];
    __syncthreads();
    float acc[4][4];
#pragma unroll
    for (int oo = 0; oo < 4; ++oo)
#pragma unroll
      for (int dt = 0; dt < 4; ++dt) acc[oo][dt] = bbuf[o0 + oo];
    for (int c = 0; c < 32; ++c) {
      const float* yr = &ybuf[c * TP];
      float yv[4][3];
#pragma unroll
      for (int dt = 0; dt < 4; ++dt)
#pragma unroll
        for (int kk = 0; kk < 3; ++kk) {
          int tt = t0 + dt - (2 - kk) * dil;
          yv[dt][kk] = (tt >= 0) ? yr[tt] : 0.f;
        }
      const float* wr = &wbuf[(o0 * 32 + c) * 3];
#pragma unroll
      for (int oo = 0; oo < 4; ++oo) {
        float w0 = wr[oo * 96 + 0], w1 = wr[oo * 96 + 1], w2 = wr[oo * 96 + 2];
#pragma unroll
        for (int dt = 0; dt < 4; ++dt)
          acc[oo][dt] += w0 * yv[dt][0] + w1 * yv[dt][1] + w2 * yv[dt][2];
      }
    }
#pragma unroll
    for (int oo = 0; oo < 4; ++oo)
#pragma unroll
      for (int dt = 0; dt < 4; ++dt)
        obuf[(o0 + oo) * TP + t0 + dt] = fmaxf(acc[oo][dt], 0.f);
    __syncthreads();
    for (int idx = tid; idx < 3072; idx += 256) wbuf[idx] = w2g[blk * 3072 + idx];
    if (tid < 32) bbuf[tid] = b2g[blk * 32 + tid];
    __syncthreads();
#pragma unroll
    for (int oo = 0; oo < 4; ++oo)
#pragma unroll
      for (int dt = 0; dt < 4; ++dt) acc[oo][dt] = bbuf[o0 + oo];
    for (int c = 0; c < 32; ++c) {
      const float* yr = &obuf[c * TP];
      float yv[4][3];
#pragma unroll
      for (int dt = 0; dt < 4; ++dt)
#pragma unroll
        for (int kk = 0; kk < 3; ++kk) {
          int tt = t0 + dt - (2 - kk) * dil;
          yv[dt][kk] = (tt >= 0) ? yr[tt] : 0.f;
        }
      const float* wr = &wbuf[(o0 * 32 + c) * 3];
#pragma unroll
      for (int oo = 0; oo < 4; ++oo) {
        float w0 = wr[oo * 96 + 0], w1 = wr[oo * 96 + 1], w2 = wr[oo * 96 + 2];
#pragma unroll
        for (int dt = 0; dt < 4; ++dt)
          acc[oo][dt] += w0 * yv[dt][0] + w1 * yv[dt][1] + w2 * yv[dt][2];
      }
    }
#pragma unroll
    for (int oo = 0; oo < 4; ++oo)
#pragma unroll
      for (int dt = 0; dt < 4; ++dt) {
        float o2 = fmaxf(acc[oo][dt], 0.f);
        float y = ybuf[(o0 + oo) * TP + t0 + dt];
        ybuf[(o0 + oo) * TP + t0 + dt] = fmaxf(o2 + y, 0.f);
      }
  }
  __syncthreads();
  for (int idx = tid; idx < 4096; idx += 256) {
    int d = idx & 31, t = idx >> 5;
    yout[n * 16384 + b * 4096 + idx] = f2b(ybuf[d * TP + t]);
  }
}

// ---------------- attention: full-MFMA, both layers fused ----------------
// Per block (bn): h(128x32). Proj/scores/PV/outproj on matrix cores.
__global__ void __launch_bounds__(256) attn_kernel(
    const unsigned short* __restrict__ yin,  // bf16 [n][bt*32+d]
    float* __restrict__ outp,
    const float* __restrict__ wqg, const float* __restrict__ wkg,
    const float* __restrict__ wvg, const float* __restrict__ wog,
    const float* __restrict__ gg, const float* __restrict__ bgb) {
  __shared__ unsigned short hrow[128 * 34];  // row-major bf16 (residual/LN src)
  __shared__ unsigned short pbuf[16384];     // P A32-frags; [0..4096) = h A32-frags
  __shared__ unsigned short qfrag[4096];     // Q A16-frags; reused as O A32-frags
  __shared__ unsigned short kfrag[4096];     // K B16-frags
  __shared__ unsigned short vfrag[4096];     // V B32-frags
  int bn = blockIdx.x, tid = threadIdx.x;
  int b = bn >> 9, n = bn & 511;
  int lane = tid & 63, wave = tid >> 6;
  int l15 = lane & 15, quad = lane >> 4;
  int mt0 = wave * 2;  // this wave owns m-tiles {mt0, mt0+1}

  const unsigned short* src = yin + n * 16384 + b * 4096;
  for (int idx = tid; idx < 4096; idx += 256) {
    int t = idx >> 5, c = idx & 31;
    unsigned short v = src[idx];
    hrow[t * 34 + c] = v;
    pbuf[((t >> 4) * 4 + (c >> 3)) * 128 + (t & 15) * 8 + (c & 7)] = v;
  }

  for (int L = 0; L < 2; ++L) {
    if (L) {
      __syncthreads();  // hrow writes done (epilogue L0)
      for (int idx = tid; idx < 4096; idx += 256) {
        int t = idx >> 5, c = idx & 31;
        pbuf[((t >> 4) * 4 + (c >> 3)) * 128 + (t & 15) * 8 + (c & 7)] =
            hrow[t * 34 + c];
      }
    }
    // weight B-frags in regs: wf[m][nt], lane holds W[quad*8+j][nt*16+l15]
    const float* wmat0 = wqg + L * 1024;
    const float* wmat1 = wkg + L * 1024;
    const float* wmat2 = wvg + L * 1024;
    const float* wmat3 = wog + L * 1024;
    short8 wf[4][2];
#pragma unroll
    for (int nt = 0; nt < 2; ++nt)
#pragma unroll
      for (int j = 0; j < 8; ++j) {
        int ri = (quad * 8 + j) * 32 + nt * 16 + l15;
        wf[0][nt][j] = (short)f2b(wmat0[ri] * 0.25f);  // scale folded into Q
        wf[1][nt][j] = (short)f2b(wmat1[ri]);
        wf[2][nt][j] = (short)f2b(wmat2[ri]);
        wf[3][nt][j] = (short)f2b(wmat3[ri]);
      }
    __syncthreads();  // hfrag (pbuf) ready
    // ---- projections ----
    float4v qa_[2][2], ka_[2][2], va_[2][2];
#pragma unroll
    for (int mm = 0; mm < 2; ++mm) {
      short8 af = *(const short8*)&pbuf[((mt0 + mm) * 4 + quad) * 128 + l15 * 8];
#pragma unroll
      for (int nt = 0; nt < 2; ++nt) {
        qa_[mm][nt] = MFMA32(af, wf[0][nt], (float4v)0.f);
        ka_[mm][nt] = MFMA32(af, wf[1][nt], (float4v)0.f);
        va_[mm][nt] = MFMA32(af, wf[2][nt], (float4v)0.f);
      }
    }
    // write Q/K/V fragments (C-frag -> operand layouts)
#pragma unroll
    for (int mm = 0; mm < 2; ++mm) {
      int mtq = mt0 + mm;
#pragma unroll
      for (int nt = 0; nt < 2; ++nt)
#pragma unroll
        for (int r = 0; r < 4; ++r) {
          qfrag[(((mtq * 2 + nt) * 4 + (l15 >> 2)) * 16 + quad * 4 + r) * 4 +
                (l15 & 3)] = f2b(qa_[mm][nt][r]);
          kfrag[(((nt * 8 + mtq) * 4 + (l15 >> 2)) * 16 + quad * 4 + r) * 4 +
                (l15 & 3)] = f2b(ka_[mm][nt][r]);
          vfrag[((((mtq >> 1) * 4 + (mtq & 1) * 2 + (quad >> 1)) * 32 +
                  nt * 16 + l15)) * 8 + (quad & 1) * 4 + r] = f2b(va_[mm][nt][r]);
        }
    }
    __syncthreads();  // frags ready; also: all hfrag reads done before P writes
    // ---- per-head scores/softmax/PV ----
    float4v oacc[2][2];
#pragma unroll
    for (int mm = 0; mm < 2; ++mm)
#pragma unroll
      for (int hh = 0; hh < 2; ++hh) oacc[mm][hh] = (float4v)0.f;
    for (int hh = 0; hh < 2; ++hh) {
      float4v sacc[2][8];
      short4v qa[2];
#pragma unroll
      for (int mm = 0; mm < 2; ++mm)
        qa[mm] = *(const short4v*)&qfrag[((((mt0 + mm) * 2 + hh) * 4 + quad) * 16 +
                                          l15) * 4];
#pragma unroll
      for (int st = 0; st < 8; ++st) {
        short4v kb = *(const short4v*)&kfrag[(((hh * 8 + st) * 4 + quad) * 16 +
                                              l15) * 4];
#pragma unroll
        for (int mm = 0; mm < 2; ++mm) sacc[mm][st] = MFMA16(qa[mm], kb);
      }
      // softmax per row (t = mt*16 + quad*4 + r), s spread over st x l15
#pragma unroll
      for (int mm = 0; mm < 2; ++mm)
#pragma unroll
        for (int r = 0; r < 4; ++r) {
          float mx = -1e30f;
#pragma unroll
          for (int st = 0; st < 8; ++st) mx = fmaxf(mx, sacc[mm][st][r]);
          for (int m = 1; m < 16; m <<= 1) mx = fmaxf(mx, __shfl_xor(mx, m));
          float sum = 0.f;
#pragma unroll
          for (int st = 0; st < 8; ++st) {
            float e = __expf(sacc[mm][st][r] - mx);
            sacc[mm][st][r] = e;
            sum += e;
          }
          for (int m = 1; m < 16; m <<= 1) sum += __shfl_xor(sum, m);
          float inv = 1.f / sum;
#pragma unroll
          for (int st = 0; st < 8; ++st) sacc[mm][st][r] *= inv;
        }
      // write P in A32 layout (own m-tiles only -> wave-local, no barrier)
#pragma unroll
      for (int mm = 0; mm < 2; ++mm) {
        int mtq = mt0 + mm;
#pragma unroll
        for (int st = 0; st < 8; ++st)
#pragma unroll
          for (int r = 0; r < 4; ++r)
            pbuf[((mtq * 4 + (st >> 1)) * 4 + (st & 1) * 2 + (l15 >> 3)) * 128 +
                 (quad * 4 + r) * 8 + (l15 & 7)] = f2b(sacc[mm][st][r]);
      }
      // PV: O_h += P @ V_h
#pragma unroll
      for (int mm = 0; mm < 2; ++mm)
#pragma unroll
        for (int ks = 0; ks < 4; ++ks) {
          short8 pa = *(const short8*)&pbuf[(((mt0 + mm) * 4 + ks) * 4 + quad) *
                                                128 + l15 * 8];
          short8 vb = *(const short8*)&vfrag[((ks * 4 + quad) * 32 + hh * 16 +
                                              l15) * 8];
          oacc[mm][hh] = MFMA32(pa, vb, oacc[mm][hh]);
        }
    }
    // ---- output projection ----
#pragma unroll
    for (int mm = 0; mm < 2; ++mm) {
      int mtq = mt0 + mm;
#pragma unroll
      for (int hh = 0; hh < 2; ++hh)
#pragma unroll
        for (int r = 0; r < 4; ++r)
          qfrag[((mtq * 4 + hh * 2 + (l15 >> 3)) << 7) + (quad * 4 + r) * 8 +
                (l15 & 7)] = f2b(oacc[mm][hh][r]);
    }
    float4v racc[2][2];
#pragma unroll
    for (int mm = 0; mm < 2; ++mm) {
      short8 ofa = *(const short8*)&qfrag[(((mt0 + mm) * 4 + quad) << 7) + l15 * 8];
#pragma unroll
      for (int nt = 0; nt < 2; ++nt) racc[mm][nt] = MFMA32(ofa, wf[3][nt], (float4v)0.f);
    }
    // ---- residual + layernorm epilogue ----
    float gam0 = gg[L * 32 + l15], bet0 = bgb[L * 32 + l15];
    float gam1 = gg[L * 32 + 16 + l15], bet1 = bgb[L * 32 + 16 + l15];
#pragma unroll
    for (int mm = 0; mm < 2; ++mm) {
      int mtq = mt0 + mm;
#pragma unroll
      for (int r = 0; r < 4; ++r) {
        int t = mtq * 16 + quad * 4 + r;
        float v0 = racc[mm][0][r] + b2f(hrow[t * 34 + l15]);
        float v1 = racc[mm][1][r] + b2f(hrow[t * 34 + 16 + l15]);
        float s = v0 + v1;
        for (int m = 1; m < 16; m <<= 1) s += __shfl_xor(s, m);
        float mu = s * 0.03125f;
        float d0 = v0 - mu, d1 = v1 - mu;
        float q = d0 * d0 + d1 * d1;
        for (int m = 1; m < 16; m <<= 1) q += __shfl_xor(q, m);
        float rs = rsqrtf(q * 0.03125f + 1e-5f);
        float y0 = d0 * rs * gam0 + bet0;
        float y1 = d1 * rs * gam1 + bet1;
        if (L == 0) {
          hrow[t * 34 + l15] = f2b(y0);        // same (t,o) this thread read
          hrow[t * 34 + 16 + l15] = f2b(y1);
        } else {
          outp[((b * 128 + t) * 512 + n) * 32 + l15] = y0;
          outp[((b * 128 + t) * 512 + n) * 32 + 16 + l15] = y1;
        }
      }
    }
  }
}

extern "C" void kernel_launch(void* const* d_in, const int* in_sizes, int n_in,
                              void* d_out, int out_size, void* d_ws, size_t ws_size,
                              hipStream_t stream) {
  const float* x    = (const float*)d_in[0];
  const float* emb  = (const float*)d_in[2];
  const float* adj  = (const float*)d_in[3];
  const float* gw   = (const float*)d_in[4];
  const float* gb   = (const float*)d_in[5];
  const float* tw1  = (const float*)d_in[6];
  const float* tb1  = (const float*)d_in[7];
  const float* tw2  = (const float*)d_in[8];
  const float* tb2  = (const float*)d_in[9];
  const float* wq   = (const float*)d_in[10];
  const float* wk   = (const float*)d_in[11];
  const float* wv   = (const float*)d_in[12];
  const float* wo   = (const float*)d_in[13];
  const float* tg   = (const float*)d_in[14];
  const float* tbb  = (const float*)d_in[15];
  float* outp = (float*)d_out;

  char* p = (char*)d_ws;
  unsigned short* Sb = (unsigned short*)p;  p += 1048576;
  float* Wn          = (float*)p;           p += 18874368;
  float* biasn       = (float*)p;           p += 196608;
  float* G           = (float*)p;           p += 67108864;
  unsigned short* H8a = (unsigned short*)p; p += 16777216;
  unsigned short* H8b = (unsigned short*)p; p += 16777216;
  unsigned short* ypl = (unsigned short*)p; p += 16777216;

  prep_supports<<<dim3(512), dim3(256), 0, stream>>>(adj, Sb);
  prep_w_kernel<<<dim3(1536), dim3(256), 0, stream>>>(emb, gw, gb, Wn, biasn);
  conv_x<<<dim3(512), dim3(256), 0, stream>>>(x, H8a);

  gcn_phaseA<<<dim3(1024), dim3(256), 0, stream>>>(Sb, H8a, G);
  gcn_phaseB<<<dim3(512), dim3(256), 0, stream>>>(H8a, G, Wn, biasn, H8b);
  gcn_phaseA<<<dim3(1024), dim3(256), 0, stream>>>(Sb, H8b, G);
  gcn_phaseB<<<dim3(512), dim3(256), 0, stream>>>(H8b, G, Wn + 1572864,
                                                  biasn + 16384, H8a);
  gcn_phaseA<<<dim3(1024), dim3(256), 0, stream>>>(Sb, H8a, G);
  gcn_phaseB<<<dim3(512), dim3(256), 0, stream>>>(H8a, G, Wn + 3145728,
                                                  biasn + 32768, H8b);

  tcn_kernel<<<dim3(2048), dim3(256), 0, stream>>>(H8b, ypl, tw1, tb1, tw2, tb2);
  attn_kernel<<<dim3(2048), dim3(256), 0, stream>>>(ypl, outp, wq, wk, wv, wo,
                                                    tg, tbb);
}

// Round 5
// 639.027 us; speedup vs baseline: 5.1010x; 1.9526x over previous
//
#include <hip/hip_runtime.h>

// B=4, T=128, N=512, D=32, CHEB_K=3, EMB=10, HEADS=2, TA_LAYERS=2, GCN_NUM=3,
// TCN_BLOCKS=3, KSIZE=3.  Inputs/outputs fp32; internal bf16 + MFMA.

typedef __attribute__((ext_vector_type(8))) short short8;
typedef __attribute__((ext_vector_type(4))) short short4v;
typedef __attribute__((ext_vector_type(4))) float float4v;

#define MFMA32(a, b, c) __builtin_amdgcn_mfma_f32_16x16x32_bf16((a), (b), (c), 0, 0, 0)
#if defined(__has_builtin)
#if __has_builtin(__builtin_amdgcn_mfma_f32_16x16x16_bf16)
#define MFMA16(a, b) __builtin_amdgcn_mfma_f32_16x16x16_bf16((a), (b), (float4v)0.f, 0, 0, 0)
#elif __has_builtin(__builtin_amdgcn_mfma_f32_16x16x16bf16_1k)
#define MFMA16(a, b) __builtin_amdgcn_mfma_f32_16x16x16bf16_1k((a), (b), (float4v)0.f, 0, 0, 0)
#endif
#endif
#ifndef MFMA16
#define MFMA16(a, b) __builtin_amdgcn_mfma_f32_16x16x16bf16_1k((a), (b), (float4v)0.f, 0, 0, 0)
#endif

__device__ __forceinline__ unsigned short f2b(float f) {
  unsigned int x = __float_as_uint(f);
  unsigned int r = (x + 0x7fffu + ((x >> 16) & 1u)) >> 16;
  return (unsigned short)r;
}
__device__ __forceinline__ float b2f(unsigned short u) {
  return __uint_as_float(((unsigned int)u) << 16);
}

// ---------------- prep: supports in bf16 ----------------
__global__ void __launch_bounds__(256) prep_supports(
    const float* __restrict__ adj, unsigned short* __restrict__ Sb) {
  __shared__ float arow[512];
  int n = blockIdx.x, tid = threadIdx.x;
  for (int m = tid; m < 512; m += 256) {
    float v = adj[n * 512 + m];
    arow[m] = v;
    Sb[n * 512 + m] = f2b(v);
  }
  __syncthreads();
  for (int m = tid; m < 512; m += 256) {
    float acc = 0.f;
    for (int p = 0; p < 512; ++p) acc += arow[p] * adj[p * 512 + m];
    Sb[(512 + n) * 512 + m] = f2b(2.f * acc - (m == n ? 1.f : 0.f));
  }
}

// ---------------- prep: per-node GCN weights ----------------
__global__ void __launch_bounds__(256) prep_w_kernel(
    const float* __restrict__ emb, const float* __restrict__ gw,
    const float* __restrict__ gb,
    float* __restrict__ Wn, float* __restrict__ biasn) {
  int bid = blockIdx.x;  // 0..1535
  int i = bid >> 9, n = bid & 511, tid = threadIdx.x;
  float ev[10];
#pragma unroll
  for (int e = 0; e < 10; ++e) ev[e] = emb[n * 10 + e];
  for (int idx = tid; idx < 3072; idx += 256) {
    float acc = 0.f;
#pragma unroll
    for (int e = 0; e < 10; ++e) acc += ev[e] * gw[(i * 10 + e) * 3072 + idx];
    Wn[(i * 512 + n) * 3072 + idx] = acc;
  }
  if (tid < 32) {
    float acc = 0.f;
#pragma unroll
    for (int e = 0; e < 10; ++e) acc += ev[e] * gb[(i * 10 + e) * 32 + tid];
    biasn[(i * 512 + n) * 32 + tid] = acc;
  }
}

// ---------------- prep: TCN weights -> bf16 A-frag layout ----------------
// Wt[(blk*2+conv)*3+kk][o][c] = w{1,2}g[blk][o][c][kk]
__global__ void __launch_bounds__(256) prep_tw(
    const float* __restrict__ w1g, const float* __restrict__ w2g,
    unsigned short* __restrict__ Wt) {
  int bid = blockIdx.x;  // 6 = blk(3) x conv(2)
  int blk = bid >> 1, conv = bid & 1;
  const float* w = (conv ? w2g : w1g) + blk * 3072;
  for (int idx = threadIdx.x; idx < 3072; idx += 256) {
    int kk = idx >> 10, rem = idx & 1023;
    int o = rem >> 5, c = rem & 31;
    Wt[bid * 3072 + idx] = f2b(w[o * 96 + c * 3 + kk]);
  }
}

// ---------------- x -> H8 swizzled bf16 ----------------
__global__ void __launch_bounds__(256) conv_x(
    const float* __restrict__ x, unsigned short* __restrict__ H8) {
  int bid = blockIdx.x;  // 512 = nblk(64) x btc(8)
  int nblk = bid >> 3, btc = bid & 7;
  int tid = threadIdx.x, s = tid >> 5, c = tid & 31;
  for (int bti = 0; bti < 64; ++bti) {
    int bt = btc * 64 + bti;
    float v = x[bt * 16384 + nblk * 256 + tid];
    H8[nblk * 131072 + (bt * 32 + c) * 8 + s] = f2b(v);
  }
}

// ---------------- GCN phase A: G = S @ H  (MFMA) ----------------
#define AST 40
__global__ void __launch_bounds__(256) gcn_phaseA(
    const unsigned short* __restrict__ Sb,
    const unsigned short* __restrict__ H8,
    float* __restrict__ G) {
  __shared__ unsigned short As[128 * AST];
  __shared__ unsigned short Bs[4096];
  int bid = blockIdx.x;  // 1024 = jt(128) x mt(8)
  int mt = bid & 7, jt = bid >> 3;
  int m0 = mt * 128, j0 = jt * 128;
  int tid = threadIdx.x;
  int wave = tid >> 6, lane = tid & 63;
  int wm = wave >> 1, wj = wave & 1;
  int l15 = lane & 15, quad = lane >> 4;
  float4v acc[4][4];
#pragma unroll
  for (int a = 0; a < 4; ++a)
#pragma unroll
    for (int b = 0; b < 4; ++b) acc[a][b] = (float4v)0.f;
  for (int nc = 0; nc < 512; nc += 32) {
#pragma unroll
    for (int p = 0; p < 2; ++p) {
      int q = tid + p * 256;
      int m = q >> 2, seg = q & 3;
      *(uint4*)&As[m * AST + seg * 8] =
          *(const uint4*)&Sb[(m0 + m) * 512 + nc + seg * 8];
    }
    const unsigned short* hb = H8 + (nc >> 3) * 131072 + j0 * 8;
#pragma unroll
    for (int p = 0; p < 2; ++p) {
      int q = tid + p * 256;
      int nb = q >> 7, rem = q & 127;
      *(uint4*)&Bs[nb * 1024 + rem * 8] =
          *(const uint4*)&hb[nb * 131072 + rem * 8];
    }
    __syncthreads();
    short8 af[4], bfr[4];
#pragma unroll
    for (int mi = 0; mi < 4; ++mi)
      af[mi] = *(const short8*)&As[(wm * 64 + mi * 16 + l15) * AST + quad * 8];
#pragma unroll
    for (int ji = 0; ji < 4; ++ji)
      bfr[ji] = *(const short8*)&Bs[quad * 1024 + (wj * 64 + ji * 16 + l15) * 8];
#pragma unroll
    for (int mi = 0; mi < 4; ++mi)
#pragma unroll
      for (int ji = 0; ji < 4; ++ji)
        acc[mi][ji] = MFMA32(af[mi], bfr[ji], acc[mi][ji]);
    __syncthreads();
  }
#pragma unroll
  for (int mi = 0; mi < 4; ++mi)
#pragma unroll
    for (int ji = 0; ji < 4; ++ji) {
      int j = j0 + wj * 64 + ji * 16 + l15;
#pragma unroll
      for (int r = 0; r < 4; ++r) {
        int m = m0 + wm * 64 + mi * 16 + quad * 4 + r;
        G[m * 16384 + j] = acc[mi][ji][r];
      }
    }
}

// ---------------- GCN phase B: per-node weight apply ----------------
// out_mode 0: H8 n-interleave.  out_mode 1: TCN layout [n][b][cg][t][ci].
#define XST 132
__global__ void __launch_bounds__(256) gcn_phaseB(
    const unsigned short* __restrict__ H8in, const float* __restrict__ G,
    const float* __restrict__ Wn, const float* __restrict__ biasn,
    unsigned short* __restrict__ H8out, int out_mode) {
  __shared__ float Xl[3][32 * XST];
  __shared__ float Wl[3072];
  int bid = blockIdx.x;  // 512 = nblk(64) x btc(4) x nih(2)
  int nih = bid & 1, btc = (bid >> 1) & 3, nblk = bid >> 3;
  int bt0 = btc * 128;
  int tid = threadIdx.x;
  int o4 = (tid & 7) * 4, btq = tid >> 3;
  for (int nii = 0; nii < 4; ++nii) {
    int ni = nih * 4 + nii;
    int n = nblk * 8 + ni;
    for (int e = tid; e < 3072; e += 256) Wl[e] = Wn[n * 3072 + e];
#pragma unroll
    for (int p = 0; p < 4; ++p) {
      int idx = tid + p * 256;  // 1024: bt(128) x c4(8)
      int bt = idx >> 3, c4 = idx & 7;
      int jb = (bt0 + bt) * 32 + c4 * 4;
#pragma unroll
      for (int u = 0; u < 4; ++u)
        Xl[0][(c4 * 4 + u) * XST + bt] =
            b2f(H8in[nblk * 131072 + (jb + u) * 8 + ni]);
      float4 g1 = *(const float4*)&G[n * 16384 + jb];
      float4 g2 = *(const float4*)&G[(512 + n) * 16384 + jb];
      Xl[1][(c4 * 4 + 0) * XST + bt] = g1.x;
      Xl[1][(c4 * 4 + 1) * XST + bt] = g1.y;
      Xl[1][(c4 * 4 + 2) * XST + bt] = g1.z;
      Xl[1][(c4 * 4 + 3) * XST + bt] = g1.w;
      Xl[2][(c4 * 4 + 0) * XST + bt] = g2.x;
      Xl[2][(c4 * 4 + 1) * XST + bt] = g2.y;
      Xl[2][(c4 * 4 + 2) * XST + bt] = g2.z;
      Xl[2][(c4 * 4 + 3) * XST + bt] = g2.w;
    }
    __syncthreads();
    float acc[4][4];
#pragma unroll
    for (int a = 0; a < 4; ++a)
#pragma unroll
      for (int b = 0; b < 4; ++b) acc[a][b] = 0.f;
    for (int k = 0; k < 3; ++k)
#pragma unroll 4
      for (int c = 0; c < 32; ++c) {
        float4 w = *(const float4*)&Wl[(k * 32 + c) * 32 + o4];
        float4 xv = *(const float4*)&Xl[k][c * XST + btq * 4];
        float xx[4] = {xv.x, xv.y, xv.z, xv.w};
        float ww[4] = {w.x, w.y, w.z, w.w};
#pragma unroll
        for (int bi = 0; bi < 4; ++bi)
#pragma unroll
          for (int oi = 0; oi < 4; ++oi) acc[bi][oi] += xx[bi] * ww[oi];
      }
    float4 bs = *(const float4*)&biasn[n * 32 + o4];
    float bb[4] = {bs.x, bs.y, bs.z, bs.w};
#pragma unroll
    for (int bi = 0; bi < 4; ++bi) {
      int bt = bt0 + btq * 4 + bi;
      if (out_mode == 0) {
#pragma unroll
        for (int oi = 0; oi < 4; ++oi)
          H8out[nblk * 131072 + (bt * 32 + o4 + oi) * 8 + ni] =
              f2b(acc[bi][oi] + bb[oi]);
      } else {
        int b = bt >> 7, t = bt & 127;
#pragma unroll
        for (int oi = 0; oi < 4; ++oi) {
          int o = o4 + oi;
          H8out[n * 16384 + b * 4096 + (o >> 3) * 1024 + t * 8 + (o & 7)] =
              f2b(acc[bi][oi] + bb[oi]);
        }
      }
    }
    __syncthreads();
  }
}

// ---------------- TCN: wave-per-(b,n), full MFMA, no barriers ----------
// Yin: [n][b][cg][t][ci] bf16.  yout: [n][b][t*32+o] bf16.
// LDS per wave: Y8/O8 in [cg(4)][t(136: 8 pad + 128)][ci(8)] bf16.
__global__ void __launch_bounds__(256) tcn_kernel(
    const unsigned short* __restrict__ Yin, unsigned short* __restrict__ yout,
    const unsigned short* __restrict__ Wt,
    const float* __restrict__ b1g, const float* __restrict__ b2g) {
  __shared__ unsigned short Y8[4][4352];
  __shared__ unsigned short O8[4][4352];
  int tid = threadIdx.x, wave = tid >> 6, lane = tid & 63;
  int l15 = lane & 15, quad = lane >> 4;
  int n = blockIdx.x, b = wave;
  unsigned short* y8 = &Y8[wave][0];
  unsigned short* o8 = &O8[wave][0];
  // zero t-pad region (t-slots 0..7): 128 b64 chunks over 2 buffers
  {
    int cg = lane >> 4, t = (lane >> 1) & 7, half = lane & 1;
    ushort4 z = {0, 0, 0, 0};
    *(ushort4*)&y8[(cg * 136 + t) * 8 + half * 4] = z;
    *(ushort4*)&o8[(cg * 136 + t) * 8 + half * 4] = z;
  }
  // stage y
  const unsigned short* src = Yin + n * 16384 + b * 4096;
#pragma unroll
  for (int p = 0; p < 8; ++p) {
    int e = p * 64 + lane;  // 512 chunks of 8 bf16
    int cg = e >> 7, t = e & 127;
    *(uint4*)&y8[(cg * 136 + t + 8) * 8] = *(const uint4*)&src[e * 8];
  }
  for (int blk = 0; blk < 3; ++blk) {
    int dil = 1 << blk;
    for (int conv = 0; conv < 2; ++conv) {
      const unsigned short* wbase = Wt + ((blk * 2 + conv) * 3) * 1024;
      short8 af[2][3];
#pragma unroll
      for (int mt = 0; mt < 2; ++mt)
#pragma unroll
        for (int kk = 0; kk < 3; ++kk)
          af[mt][kk] = *(const short8*)&wbase[kk * 1024 +
                                              (mt * 16 + l15) * 32 + quad * 8];
      const float* bias = (conv ? b2g : b1g) + blk * 32;
      float4 bs0 = *(const float4*)&bias[quad * 4];
      float4 bs1 = *(const float4*)&bias[16 + quad * 4];
      float bb0[4] = {bs0.x, bs0.y, bs0.z, bs0.w};
      float bb1[4] = {bs1.x, bs1.y, bs1.z, bs1.w};
      const unsigned short* rbuf = conv ? o8 : y8;
#pragma unroll 2
      for (int nt = 0; nt < 8; ++nt) {
        float4v acc0 = (float4v)0.f, acc1 = (float4v)0.f;
#pragma unroll
        for (int kk = 0; kk < 3; ++kk) {
          int tb = nt * 16 + l15 + 8 - (2 - kk) * dil;
          short8 bf = *(const short8*)&rbuf[(quad * 136 + tb) * 8];
          acc0 = MFMA32(af[0][kk], bf, acc0);
          acc1 = MFMA32(af[1][kk], bf, acc1);
        }
        int t8 = nt * 16 + l15 + 8;
        // o-group addressing: o = mt*16 + quad*4 + r; 4 r contiguous in ci
        int og0 = (quad >> 1), ci0 = (quad & 1) * 4;
        if (conv == 0) {
          ushort4 w0, w1;
          w0.x = f2b(fmaxf(acc0[0] + bb0[0], 0.f));
          w0.y = f2b(fmaxf(acc0[1] + bb0[1], 0.f));
          w0.z = f2b(fmaxf(acc0[2] + bb0[2], 0.f));
          w0.w = f2b(fmaxf(acc0[3] + bb0[3], 0.f));
          w1.x = f2b(fmaxf(acc1[0] + bb1[0], 0.f));
          w1.y = f2b(fmaxf(acc1[1] + bb1[1], 0.f));
          w1.z = f2b(fmaxf(acc1[2] + bb1[2], 0.f));
          w1.w = f2b(fmaxf(acc1[3] + bb1[3], 0.f));
          *(ushort4*)&o8[((og0)*136 + t8) * 8 + ci0] = w0;
          *(ushort4*)&o8[((2 + og0) * 136 + t8) * 8 + ci0] = w1;
        } else {
          ushort4 y0 = *(const ushort4*)&y8[((og0)*136 + t8) * 8 + ci0];
          ushort4 y1 = *(const ushort4*)&y8[((2 + og0) * 136 + t8) * 8 + ci0];
          ushort4 w0, w1;
          w0.x = f2b(fmaxf(fmaxf(acc0[0] + bb0[0], 0.f) + b2f(y0.x), 0.f));
          w0.y = f2b(fmaxf(fmaxf(acc0[1] + bb0[1], 0.f) + b2f(y0.y), 0.f));
          w0.z = f2b(fmaxf(fmaxf(acc0[2] + bb0[2], 0.f) + b2f(y0.z), 0.f));
          w0.w = f2b(fmaxf(fmaxf(acc0[3] + bb0[3], 0.f) + b2f(y0.w), 0.f));
          w1.x = f2b(fmaxf(fmaxf(acc1[0] + bb1[0], 0.f) + b2f(y1.x), 0.f));
          w1.y = f2b(fmaxf(fmaxf(acc1[1] + bb1[1], 0.f) + b2f(y1.y), 0.f));
          w1.z = f2b(fmaxf(fmaxf(acc1[2] + bb1[2], 0.f) + b2f(y1.z), 0.f));
          w1.w = f2b(fmaxf(fmaxf(acc1[3] + bb1[3], 0.f) + b2f(y1.w), 0.f));
          *(ushort4*)&y8[((og0)*136 + t8) * 8 + ci0] = w0;
          *(ushort4*)&y8[((2 + og0) * 136 + t8) * 8 + ci0] = w1;
        }
      }
    }
  }
  // write out: [t*32 + o] contiguous per (og, t) chunk
  unsigned short* dst = yout + n * 16384 + b * 4096;
#pragma unroll
  for (int p = 0; p < 8; ++p) {
    int e = p * 64 + lane;
    int og = e >> 7, t = e & 127;
    *(uint4*)&dst[t * 32 + og * 8] = *(const uint4*)&y8[(og * 136 + t + 8) * 8];
  }
}

// ---------------- attention: full-MFMA, both layers fused ----------------
__global__ void __launch_bounds__(256) attn_kernel(
    const unsigned short* __restrict__ yin,  // bf16 [n][b][t*32+d]
    float* __restrict__ outp,
    const float* __restrict__ wqg, const float* __restrict__ wkg,
    const float* __restrict__ wvg, const float* __restrict__ wog,
    const float* __restrict__ gg, const float* __restrict__ bgb) {
  __shared__ unsigned short hrow[128 * 34];  // row-major bf16 (residual/LN src)
  __shared__ unsigned short pbuf[16384];     // P A32-frags; [0..4096) = h A32-frags
  __shared__ unsigned short qfrag[4096];     // Q A16-frags; reused as O A32-frags
  __shared__ unsigned short kfrag[4096];     // K B16-frags
  __shared__ unsigned short vfrag[4096];     // V B32-frags
  int bn = blockIdx.x, tid = threadIdx.x;
  int b = bn >> 9, n = bn & 511;
  int lane = tid & 63, wave = tid >> 6;
  int l15 = lane & 15, quad = lane >> 4;
  int mt0 = wave * 2;  // this wave owns m-tiles {mt0, mt0+1}

  const unsigned short* src = yin + n * 16384 + b * 4096;
  for (int idx = tid; idx < 4096; idx += 256) {
    int t = idx >> 5, c = idx & 31;
    unsigned short v = src[idx];
    hrow[t * 34 + c] = v;
    pbuf[((t >> 4) * 4 + (c >> 3)) * 128 + (t & 15) * 8 + (c & 7)] = v;
  }

  for (int L = 0; L < 2; ++L) {
    if (L) {
      __syncthreads();  // hrow writes done (epilogue L0)
      for (int idx = tid; idx < 4096; idx += 256) {
        int t = idx >> 5, c = idx & 31;
        pbuf[((t >> 4) * 4 + (c >> 3)) * 128 + (t & 15) * 8 + (c & 7)] =
            hrow[t * 34 + c];
      }
    }
    const float* wmat0 = wqg + L * 1024;
    const float* wmat1 = wkg + L * 1024;
    const float* wmat2 = wvg + L * 1024;
    const float* wmat3 = wog + L * 1024;
    short8 wf[4][2];
#pragma unroll
    for (int nt = 0; nt < 2; ++nt)
#pragma unroll
      for (int j = 0; j < 8; ++j) {
        int ri = (quad * 8 + j) * 32 + nt * 16 + l15;
        wf[0][nt][j] = (short)f2b(wmat0[ri] * 0.25f);  // scale folded into Q
        wf[1][nt][j] = (short)f2b(wmat1[ri]);
        wf[2][nt][j] = (short)f2b(wmat2[ri]);
        wf[3][nt][j] = (short)f2b(wmat3[ri]);
      }
    __syncthreads();  // hfrag (pbuf) ready
    float4v qa_[2][2], ka_[2][2], va_[2][2];
#pragma unroll
    for (int mm = 0; mm < 2; ++mm) {
      short8 af = *(const short8*)&pbuf[((mt0 + mm) * 4 + quad) * 128 + l15 * 8];
#pragma unroll
      for (int nt = 0; nt < 2; ++nt) {
        qa_[mm][nt] = MFMA32(af, wf[0][nt], (float4v)0.f);
        ka_[mm][nt] = MFMA32(af, wf[1][nt], (float4v)0.f);
        va_[mm][nt] = MFMA32(af, wf[2][nt], (float4v)0.f);
      }
    }
#pragma unroll
    for (int mm = 0; mm < 2; ++mm) {
      int mtq = mt0 + mm;
#pragma unroll
      for (int nt = 0; nt < 2; ++nt)
#pragma unroll
        for (int r = 0; r < 4; ++r) {
          qfrag[(((mtq * 2 + nt) * 4 + (l15 >> 2)) * 16 + quad * 4 + r) * 4 +
                (l15 & 3)] = f2b(qa_[mm][nt][r]);
          kfrag[(((nt * 8 + mtq) * 4 + (l15 >> 2)) * 16 + quad * 4 + r) * 4 +
                (l15 & 3)] = f2b(ka_[mm][nt][r]);
          vfrag[((((mtq >> 1) * 4 + (mtq & 1) * 2 + (quad >> 1)) * 32 +
                  nt * 16 + l15)) * 8 + (quad & 1) * 4 + r] = f2b(va_[mm][nt][r]);
        }
    }
    __syncthreads();  // frags ready
    float4v oacc[2][2];
#pragma unroll
    for (int mm = 0; mm < 2; ++mm)
#pragma unroll
      for (int hh = 0; hh < 2; ++hh) oacc[mm][hh] = (float4v)0.f;
    for (int hh = 0; hh < 2; ++hh) {
      float4v sacc[2][8];
      short4v qa[2];
#pragma unroll
      for (int mm = 0; mm < 2; ++mm)
        qa[mm] = *(const short4v*)&qfrag[((((mt0 + mm) * 2 + hh) * 4 + quad) * 16 +
                                          l15) * 4];
#pragma unroll
      for (int st = 0; st < 8; ++st) {
        short4v kb = *(const short4v*)&kfrag[(((hh * 8 + st) * 4 + quad) * 16 +
                                              l15) * 4];
#pragma unroll
        for (int mm = 0; mm < 2; ++mm) sacc[mm][st] = MFMA16(qa[mm], kb);
      }
#pragma unroll
      for (int mm = 0; mm < 2; ++mm)
#pragma unroll
        for (int r = 0; r < 4; ++r) {
          float mx = -1e30f;
#pragma unroll
          for (int st = 0; st < 8; ++st) mx = fmaxf(mx, sacc[mm][st][r]);
          for (int m = 1; m < 16; m <<= 1) mx = fmaxf(mx, __shfl_xor(mx, m));
          float sum = 0.f;
#pragma unroll
          for (int st = 0; st < 8; ++st) {
            float e = __expf(sacc[mm][st][r] - mx);
            sacc[mm][st][r] = e;
            sum += e;
          }
          for (int m = 1; m < 16; m <<= 1) sum += __shfl_xor(sum, m);
          float inv = 1.f / sum;
#pragma unroll
          for (int st = 0; st < 8; ++st) sacc[mm][st][r] *= inv;
        }
#pragma unroll
      for (int mm = 0; mm < 2; ++mm) {
        int mtq = mt0 + mm;
#pragma unroll
        for (int st = 0; st < 8; ++st)
#pragma unroll
          for (int r = 0; r < 4; ++r)
            pbuf[((mtq * 4 + (st >> 1)) * 4 + (st & 1) * 2 + (l15 >> 3)) * 128 +
                 (quad * 4 + r) * 8 + (l15 & 7)] = f2b(sacc[mm][st][r]);
      }
#pragma unroll
      for (int mm = 0; mm < 2; ++mm)
#pragma unroll
        for (int ks = 0; ks < 4; ++ks) {
          short8 pa = *(const short8*)&pbuf[(((mt0 + mm) * 4 + ks) * 4 + quad) *
                                                128 + l15 * 8];
          short8 vb = *(const short8*)&vfrag[((ks * 4 + quad) * 32 + hh * 16 +
                                              l15) * 8];
          oacc[mm][hh] = MFMA32(pa, vb, oacc[mm][hh]);
        }
    }
#pragma unroll
    for (int mm = 0; mm < 2; ++mm) {
      int mtq = mt0 + mm;
#pragma unroll
      for (int hh = 0; hh < 2; ++hh)
#pragma unroll
        for (int r = 0; r < 4; ++r)
          qfrag[((mtq * 4 + hh * 2 + (l15 >> 3)) << 7) + (quad * 4 + r) * 8 +
                (l15 & 7)] = f2b(oacc[mm][hh][r]);
    }
    float4v racc[2][2];
#pragma unroll
    for (int mm = 0; mm < 2; ++mm) {
      short8 ofa = *(const short8*)&qfrag[(((mt0 + mm) * 4 + quad) << 7) + l15 * 8];
#pragma unroll
      for (int nt = 0; nt < 2; ++nt) racc[mm][nt] = MFMA32(ofa, wf[3][nt], (float4v)0.f);
    }
    float gam0 = gg[L * 32 + l15], bet0 = bgb[L * 32 + l15];
    float gam1 = gg[L * 32 + 16 + l15], bet1 = bgb[L * 32 + 16 + l15];
#pragma unroll
    for (int mm = 0; mm < 2; ++mm) {
      int mtq = mt0 + mm;
#pragma unroll
      for (int r = 0; r < 4; ++r) {
        int t = mtq * 16 + quad * 4 + r;
        float v0 = racc[mm][0][r] + b2f(hrow[t * 34 + l15]);
        float v1 = racc[mm][1][r] + b2f(hrow[t * 34 + 16 + l15]);
        float s = v0 + v1;
        for (int m = 1; m < 16; m <<= 1) s += __shfl_xor(s, m);
        float mu = s * 0.03125f;
        float d0 = v0 - mu, d1 = v1 - mu;
        float q = d0 * d0 + d1 * d1;
        for (int m = 1; m < 16; m <<= 1) q += __shfl_xor(q, m);
        float rs = rsqrtf(q * 0.03125f + 1e-5f);
        float y0 = d0 * rs * gam0 + bet0;
        float y1 = d1 * rs * gam1 + bet1;
        if (L == 0) {
          hrow[t * 34 + l15] = f2b(y0);
          hrow[t * 34 + 16 + l15] = f2b(y1);
        } else {
          outp[((b * 128 + t) * 512 + n) * 32 + l15] = y0;
          outp[((b * 128 + t) * 512 + n) * 32 + 16 + l15] = y1;
        }
      }
    }
  }
}

extern "C" void kernel_launch(void* const* d_in, const int* in_sizes, int n_in,
                              void* d_out, int out_size, void* d_ws, size_t ws_size,
                              hipStream_t stream) {
  const float* x    = (const float*)d_in[0];
  const float* emb  = (const float*)d_in[2];
  const float* adj  = (const float*)d_in[3];
  const float* gw   = (const float*)d_in[4];
  const float* gb   = (const float*)d_in[5];
  const float* tw1  = (const float*)d_in[6];
  const float* tb1  = (const float*)d_in[7];
  const float* tw2  = (const float*)d_in[8];
  const float* tb2  = (const float*)d_in[9];
  const float* wq   = (const float*)d_in[10];
  const float* wk   = (const float*)d_in[11];
  const float* wv   = (const float*)d_in[12];
  const float* wo   = (const float*)d_in[13];
  const float* tg   = (const float*)d_in[14];
  const float* tbb  = (const float*)d_in[15];
  float* outp = (float*)d_out;

  char* p = (char*)d_ws;
  unsigned short* Sb = (unsigned short*)p;  p += 1048576;
  float* Wn          = (float*)p;           p += 18874368;
  float* biasn       = (float*)p;           p += 196608;
  float* G           = (float*)p;           p += 67108864;
  unsigned short* H8a = (unsigned short*)p; p += 16777216;
  unsigned short* H8b = (unsigned short*)p; p += 16777216;  // also TCN-in (Ybig)
  unsigned short* ypl = (unsigned short*)p; p += 16777216;  // TCN-out / attn-in
  unsigned short* Wt  = (unsigned short*)p; p += 36864;

  prep_supports<<<dim3(512), dim3(256), 0, stream>>>(adj, Sb);
  prep_w_kernel<<<dim3(1536), dim3(256), 0, stream>>>(emb, gw, gb, Wn, biasn);
  prep_tw<<<dim3(6), dim3(256), 0, stream>>>(tw1, tw2, Wt);
  conv_x<<<dim3(512), dim3(256), 0, stream>>>(x, H8a);

  gcn_phaseA<<<dim3(1024), dim3(256), 0, stream>>>(Sb, H8a, G);
  gcn_phaseB<<<dim3(512), dim3(256), 0, stream>>>(H8a, G, Wn, biasn, H8b, 0);
  gcn_phaseA<<<dim3(1024), dim3(256), 0, stream>>>(Sb, H8b, G);
  gcn_phaseB<<<dim3(512), dim3(256), 0, stream>>>(H8b, G, Wn + 1572864,
                                                  biasn + 16384, H8a, 0);
  gcn_phaseA<<<dim3(1024), dim3(256), 0, stream>>>(Sb, H8a, G);
  gcn_phaseB<<<dim3(512), dim3(256), 0, stream>>>(H8a, G, Wn + 3145728,
                                                  biasn + 32768, H8b, 1);

  tcn_kernel<<<dim3(512), dim3(256), 0, stream>>>(H8b, ypl, Wt, tb1, tb2);
  attn_kernel<<<dim3(2048), dim3(256), 0, stream>>>(ypl, outp, wq, wk, wv, wo,
                                                    tg, tbb);
}

// Round 6
// 465.150 us; speedup vs baseline: 7.0078x; 1.3738x over previous
//
#include <hip/hip_runtime.h>

// B=4, T=128, N=512, D=32, CHEB_K=3, EMB=10, HEADS=2, TA_LAYERS=2, GCN_NUM=3,
// TCN_BLOCKS=3, KSIZE=3.  Inputs/outputs fp32; internal bf16 + MFMA.

typedef __attribute__((ext_vector_type(8))) short short8;
typedef __attribute__((ext_vector_type(4))) short short4v;
typedef __attribute__((ext_vector_type(4))) float float4v;

#define MFMA32(a, b, c) __builtin_amdgcn_mfma_f32_16x16x32_bf16((a), (b), (c), 0, 0, 0)
#if defined(__has_builtin)
#if __has_builtin(__builtin_amdgcn_mfma_f32_16x16x16_bf16)
#define MFMA16A(a, b, c) __builtin_amdgcn_mfma_f32_16x16x16_bf16((a), (b), (c), 0, 0, 0)
#endif
#endif
#ifndef MFMA16A
#define MFMA16A(a, b, c) __builtin_amdgcn_mfma_f32_16x16x16bf16_1k((a), (b), (c), 0, 0, 0)
#endif

__device__ __forceinline__ unsigned short f2b(float f) {
  unsigned int x = __float_as_uint(f);
  unsigned int r = (x + 0x7fffu + ((x >> 16) & 1u)) >> 16;
  return (unsigned short)r;
}
__device__ __forceinline__ float b2f(unsigned short u) {
  return __uint_as_float(((unsigned int)u) << 16);
}

// ---------------- prep: supports in bf16 ----------------
__global__ void __launch_bounds__(256) prep_supports(
    const float* __restrict__ adj, unsigned short* __restrict__ Sb) {
  __shared__ float arow[512];
  int n = blockIdx.x, tid = threadIdx.x;
  for (int m = tid; m < 512; m += 256) {
    float v = adj[n * 512 + m];
    arow[m] = v;
    Sb[n * 512 + m] = f2b(v);
  }
  __syncthreads();
  for (int m = tid; m < 512; m += 256) {
    float acc = 0.f;
    for (int p = 0; p < 512; ++p) acc += arow[p] * adj[p * 512 + m];
    Sb[(512 + n) * 512 + m] = f2b(2.f * acc - (m == n ? 1.f : 0.f));
  }
}

// ---------------- prep: per-node GCN weights -> bf16 B-frag layout -------
// W8[((i*512+n)*3+s)*1024 + (c>>3)*256 + o*8 + (c&7)] = sum_e E[n,e]*gw[i,e,s,c,o]
__global__ void __launch_bounds__(256) prep_w_kernel(
    const float* __restrict__ emb, const float* __restrict__ gw,
    const float* __restrict__ gb,
    unsigned short* __restrict__ W8, float* __restrict__ biasn) {
  int bid = blockIdx.x;  // 0..1535
  int i = bid >> 9, n = bid & 511, tid = threadIdx.x;
  float ev[10];
#pragma unroll
  for (int e = 0; e < 10; ++e) ev[e] = emb[n * 10 + e];
  for (int idx = tid; idx < 3072; idx += 256) {
    int s = idx >> 10, c = (idx >> 5) & 31, o = idx & 31;
    float acc = 0.f;
#pragma unroll
    for (int e = 0; e < 10; ++e) acc += ev[e] * gw[(i * 10 + e) * 3072 + idx];
    W8[((i * 512 + n) * 3 + s) * 1024 + (c >> 3) * 256 + o * 8 + (c & 7)] =
        f2b(acc);
  }
  if (tid < 32) {
    float acc = 0.f;
#pragma unroll
    for (int e = 0; e < 10; ++e) acc += ev[e] * gb[(i * 10 + e) * 32 + tid];
    biasn[(i * 512 + n) * 32 + tid] = acc;
  }
}

// ---------------- prep: TCN weights -> bf16 A-frag layout ----------------
__global__ void __launch_bounds__(256) prep_tw(
    const float* __restrict__ w1g, const float* __restrict__ w2g,
    unsigned short* __restrict__ Wt) {
  int bid = blockIdx.x;  // 6 = blk(3) x conv(2)
  int blk = bid >> 1, conv = bid & 1;
  const float* w = (conv ? w2g : w1g) + blk * 3072;
  for (int idx = threadIdx.x; idx < 3072; idx += 256) {
    int kk = idx >> 10, rem = idx & 1023;
    int o = rem >> 5, c = rem & 31;
    Wt[bid * 3072 + idx] = f2b(w[o * 96 + c * 3 + kk]);
  }
}

// ---------------- x -> H8 swizzled + Hrm row-major bf16 ----------------
__global__ void __launch_bounds__(256) conv_x(
    const float* __restrict__ x, unsigned short* __restrict__ H8,
    unsigned short* __restrict__ Hrm) {
  int bid = blockIdx.x;  // 512 = nblk(64) x btc(8)
  int nblk = bid >> 3, btc = bid & 7;
  int tid = threadIdx.x, s = tid >> 5, c = tid & 31;
  for (int bti = 0; bti < 64; ++bti) {
    int bt = btc * 64 + bti;
    float v = x[bt * 16384 + nblk * 256 + tid];
    unsigned short bv = f2b(v);
    H8[nblk * 131072 + (bt * 32 + c) * 8 + s] = bv;
    Hrm[(nblk * 8 + s) * 16384 + bt * 32 + c] = bv;
  }
}

// ---------------- GCN phase A: G = S @ H  (MFMA, fp32 out) ----------------
#define AST 40
__global__ void __launch_bounds__(256) gcn_phaseA(
    const unsigned short* __restrict__ Sb,
    const unsigned short* __restrict__ H8,
    float* __restrict__ G) {
  __shared__ unsigned short As[128 * AST];
  __shared__ unsigned short Bs[4096];
  int bid = blockIdx.x;  // 1024 = jt(128) x mt(8)
  int mt = bid & 7, jt = bid >> 3;
  int m0 = mt * 128, j0 = jt * 128;
  int tid = threadIdx.x;
  int wave = tid >> 6, lane = tid & 63;
  int wm = wave >> 1, wj = wave & 1;
  int l15 = lane & 15, quad = lane >> 4;
  float4v acc[4][4];
#pragma unroll
  for (int a = 0; a < 4; ++a)
#pragma unroll
    for (int b = 0; b < 4; ++b) acc[a][b] = (float4v)0.f;
  for (int nc = 0; nc < 512; nc += 32) {
#pragma unroll
    for (int p = 0; p < 2; ++p) {
      int q = tid + p * 256;
      int m = q >> 2, seg = q & 3;
      *(uint4*)&As[m * AST + seg * 8] =
          *(const uint4*)&Sb[(m0 + m) * 512 + nc + seg * 8];
    }
    const unsigned short* hb = H8 + (nc >> 3) * 131072 + j0 * 8;
#pragma unroll
    for (int p = 0; p < 2; ++p) {
      int q = tid + p * 256;
      int nb = q >> 7, rem = q & 127;
      *(uint4*)&Bs[nb * 1024 + rem * 8] =
          *(const uint4*)&hb[nb * 131072 + rem * 8];
    }
    __syncthreads();
    short8 af[4], bfr[4];
#pragma unroll
    for (int mi = 0; mi < 4; ++mi)
      af[mi] = *(const short8*)&As[(wm * 64 + mi * 16 + l15) * AST + quad * 8];
#pragma unroll
    for (int ji = 0; ji < 4; ++ji)
      bfr[ji] = *(const short8*)&Bs[quad * 1024 + (wj * 64 + ji * 16 + l15) * 8];
#pragma unroll
    for (int mi = 0; mi < 4; ++mi)
#pragma unroll
      for (int ji = 0; ji < 4; ++ji)
        acc[mi][ji] = MFMA32(af[mi], bfr[ji], acc[mi][ji]);
    __syncthreads();
  }
#pragma unroll
  for (int mi = 0; mi < 4; ++mi)
#pragma unroll
    for (int ji = 0; ji < 4; ++ji) {
      int j = j0 + wj * 64 + ji * 16 + l15;
#pragma unroll
      for (int r = 0; r < 4; ++r) {
        int m = m0 + wm * 64 + mi * 16 + quad * 4 + r;
        G[m * 16384 + j] = acc[mi][ji][r];
      }
    }
}

// ---------------- GCN phase B: per-node MFMA weight apply ----------------
// out[bt][o] = bias[o] + sum_s X_s[bt][c] @ Wn[s][c][o];  no LDS, no barriers.
__global__ void __launch_bounds__(256) gcn_phaseB(
    const unsigned short* __restrict__ Hrm, const float* __restrict__ G,
    const unsigned short* __restrict__ W8, const float* __restrict__ biasn,
    unsigned short* __restrict__ H8out, unsigned short* __restrict__ Hrmout,
    unsigned short* __restrict__ tcnout) {
  int bid = blockIdx.x;  // 1024 = n(512) x bh(2)
  int n = bid >> 1, bh = bid & 1;
  int tid = threadIdx.x;
  int lane = tid & 63, wave = tid >> 6, l15 = lane & 15, quad = lane >> 4;
  short8 wb[3][2];
#pragma unroll
  for (int s = 0; s < 3; ++s)
#pragma unroll
    for (int nt = 0; nt < 2; ++nt)
      wb[s][nt] = *(const short8*)&W8[(n * 3 + s) * 1024 + quad * 256 +
                                      (nt * 16 + l15) * 8];
  float b0 = biasn[n * 32 + l15], b1 = biasn[n * 32 + 16 + l15];
  int n8base = (n >> 3) * 131072 + (n & 7);
#pragma unroll
  for (int mi = 0; mi < 4; ++mi) {
    int bt0 = bh * 256 + wave * 64 + mi * 16;
    int btl = bt0 + l15;
    short8 a0 = *(const short8*)&Hrm[n * 16384 + btl * 32 + quad * 8];
    const float* g1p = &G[n * 16384 + btl * 32 + quad * 8];
    const float* g2p = &G[(512 + n) * 16384 + btl * 32 + quad * 8];
    float4 g1a = *(const float4*)g1p, g1b = *(const float4*)(g1p + 4);
    float4 g2a = *(const float4*)g2p, g2b = *(const float4*)(g2p + 4);
    short8 a1, a2;
    a1[0] = (short)f2b(g1a.x); a1[1] = (short)f2b(g1a.y);
    a1[2] = (short)f2b(g1a.z); a1[3] = (short)f2b(g1a.w);
    a1[4] = (short)f2b(g1b.x); a1[5] = (short)f2b(g1b.y);
    a1[6] = (short)f2b(g1b.z); a1[7] = (short)f2b(g1b.w);
    a2[0] = (short)f2b(g2a.x); a2[1] = (short)f2b(g2a.y);
    a2[2] = (short)f2b(g2a.z); a2[3] = (short)f2b(g2a.w);
    a2[4] = (short)f2b(g2b.x); a2[5] = (short)f2b(g2b.y);
    a2[6] = (short)f2b(g2b.z); a2[7] = (short)f2b(g2b.w);
    float4v acc0 = MFMA32(a0, wb[0][0], (float4v)0.f);
    acc0 = MFMA32(a1, wb[1][0], acc0);
    acc0 = MFMA32(a2, wb[2][0], acc0);
    float4v acc1 = MFMA32(a0, wb[0][1], (float4v)0.f);
    acc1 = MFMA32(a1, wb[1][1], acc1);
    acc1 = MFMA32(a2, wb[2][1], acc1);
#pragma unroll
    for (int r = 0; r < 4; ++r) {
      int bt = bt0 + quad * 4 + r;
      unsigned short v0 = f2b(acc0[r] + b0);
      unsigned short v1 = f2b(acc1[r] + b1);
      if (tcnout) {
        int bb = bt >> 7, t = bt & 127;
        int o0 = l15, o1 = 16 + l15;
        tcnout[n * 16384 + bb * 4096 + (o0 >> 3) * 1024 + t * 8 + (o0 & 7)] = v0;
        tcnout[n * 16384 + bb * 4096 + (o1 >> 3) * 1024 + t * 8 + (o1 & 7)] = v1;
      } else {
        H8out[n8base + (bt * 32 + l15) * 8] = v0;
        H8out[n8base + (bt * 32 + 16 + l15) * 8] = v1;
        Hrmout[n * 16384 + bt * 32 + l15] = v0;
        Hrmout[n * 16384 + bt * 32 + 16 + l15] = v1;
      }
    }
  }
}

// ---------------- TCN: wave-per-(b,n), full MFMA, no barriers ----------
__global__ void __launch_bounds__(256) tcn_kernel(
    const unsigned short* __restrict__ Yin, unsigned short* __restrict__ yout,
    const unsigned short* __restrict__ Wt,
    const float* __restrict__ b1g, const float* __restrict__ b2g) {
  __shared__ unsigned short Y8[4][4352];
  __shared__ unsigned short O8[4][4352];
  int tid = threadIdx.x, wave = tid >> 6, lane = tid & 63;
  int l15 = lane & 15, quad = lane >> 4;
  int n = blockIdx.x, b = wave;
  unsigned short* y8 = &Y8[wave][0];
  unsigned short* o8 = &O8[wave][0];
  {
    int cg = lane >> 4, t = (lane >> 1) & 7, half = lane & 1;
    ushort4 z = {0, 0, 0, 0};
    *(ushort4*)&y8[(cg * 136 + t) * 8 + half * 4] = z;
    *(ushort4*)&o8[(cg * 136 + t) * 8 + half * 4] = z;
  }
  const unsigned short* src = Yin + n * 16384 + b * 4096;
#pragma unroll
  for (int p = 0; p < 8; ++p) {
    int e = p * 64 + lane;
    int cg = e >> 7, t = e & 127;
    *(uint4*)&y8[(cg * 136 + t + 8) * 8] = *(const uint4*)&src[e * 8];
  }
  for (int blk = 0; blk < 3; ++blk) {
    int dil = 1 << blk;
    for (int conv = 0; conv < 2; ++conv) {
      const unsigned short* wbase = Wt + ((blk * 2 + conv) * 3) * 1024;
      short8 af[2][3];
#pragma unroll
      for (int mt = 0; mt < 2; ++mt)
#pragma unroll
        for (int kk = 0; kk < 3; ++kk)
          af[mt][kk] = *(const short8*)&wbase[kk * 1024 +
                                              (mt * 16 + l15) * 32 + quad * 8];
      const float* bias = (conv ? b2g : b1g) + blk * 32;
      float4 bs0 = *(const float4*)&bias[quad * 4];
      float4 bs1 = *(const float4*)&bias[16 + quad * 4];
      float bb0[4] = {bs0.x, bs0.y, bs0.z, bs0.w};
      float bb1[4] = {bs1.x, bs1.y, bs1.z, bs1.w};
      const unsigned short* rbuf = conv ? o8 : y8;
#pragma unroll 2
      for (int nt = 0; nt < 8; ++nt) {
        float4v acc0 = (float4v)0.f, acc1 = (float4v)0.f;
#pragma unroll
        for (int kk = 0; kk < 3; ++kk) {
          int tb = nt * 16 + l15 + 8 - (2 - kk) * dil;
          short8 bf = *(const short8*)&rbuf[(quad * 136 + tb) * 8];
          acc0 = MFMA32(af[0][kk], bf, acc0);
          acc1 = MFMA32(af[1][kk], bf, acc1);
        }
        int t8 = nt * 16 + l15 + 8;
        int og0 = (quad >> 1), ci0 = (quad & 1) * 4;
        if (conv == 0) {
          ushort4 w0, w1;
          w0.x = f2b(fmaxf(acc0[0] + bb0[0], 0.f));
          w0.y = f2b(fmaxf(acc0[1] + bb0[1], 0.f));
          w0.z = f2b(fmaxf(acc0[2] + bb0[2], 0.f));
          w0.w = f2b(fmaxf(acc0[3] + bb0[3], 0.f));
          w1.x = f2b(fmaxf(acc1[0] + bb1[0], 0.f));
          w1.y = f2b(fmaxf(acc1[1] + bb1[1], 0.f));
          w1.z = f2b(fmaxf(acc1[2] + bb1[2], 0.f));
          w1.w = f2b(fmaxf(acc1[3] + bb1[3], 0.f));
          *(ushort4*)&o8[((og0)*136 + t8) * 8 + ci0] = w0;
          *(ushort4*)&o8[((2 + og0) * 136 + t8) * 8 + ci0] = w1;
        } else {
          ushort4 y0 = *(const ushort4*)&y8[((og0)*136 + t8) * 8 + ci0];
          ushort4 y1 = *(const ushort4*)&y8[((2 + og0) * 136 + t8) * 8 + ci0];
          ushort4 w0, w1;
          w0.x = f2b(fmaxf(fmaxf(acc0[0] + bb0[0], 0.f) + b2f(y0.x), 0.f));
          w0.y = f2b(fmaxf(fmaxf(acc0[1] + bb0[1], 0.f) + b2f(y0.y), 0.f));
          w0.z = f2b(fmaxf(fmaxf(acc0[2] + bb0[2], 0.f) + b2f(y0.z), 0.f));
          w0.w = f2b(fmaxf(fmaxf(acc0[3] + bb0[3], 0.f) + b2f(y0.w), 0.f));
          w1.x = f2b(fmaxf(fmaxf(acc1[0] + bb1[0], 0.f) + b2f(y1.x), 0.f));
          w1.y = f2b(fmaxf(fmaxf(acc1[1] + bb1[1], 0.f) + b2f(y1.y), 0.f));
          w1.z = f2b(fmaxf(fmaxf(acc1[2] + bb1[2], 0.f) + b2f(y1.z), 0.f));
          w1.w = f2b(fmaxf(fmaxf(acc1[3] + bb1[3], 0.f) + b2f(y1.w), 0.f));
          *(ushort4*)&y8[((og0)*136 + t8) * 8 + ci0] = w0;
          *(ushort4*)&y8[((2 + og0) * 136 + t8) * 8 + ci0] = w1;
        }
      }
    }
  }
  unsigned short* dst = yout + n * 16384 + b * 4096;
#pragma unroll
  for (int p = 0; p < 8; ++p) {
    int e = p * 64 + lane;
    int og = e >> 7, t = e & 127;
    *(uint4*)&dst[t * 32 + og * 8] = *(const uint4*)&y8[(og * 136 + t + 8) * 8];
  }
}

// ---------------- attention: S^T trick, P stays in registers ------------
__global__ void __launch_bounds__(256) attn_kernel(
    const unsigned short* __restrict__ yin,  // bf16 [n][b][t*32+d]
    float* __restrict__ outp,
    const float* __restrict__ wqg, const float* __restrict__ wkg,
    const float* __restrict__ wvg, const float* __restrict__ wog,
    const float* __restrict__ gg, const float* __restrict__ bgb) {
  __shared__ unsigned short hrow[128 * 34];   // residual/LN source
  __shared__ unsigned short hfrag[4096];      // h in A32-frag layout
  __shared__ unsigned short Kb[128 * 36];     // K row-major [t][d], pad 36
  __shared__ unsigned short QT[32 * 136];     // Q^T [d][t], pad 136
  __shared__ unsigned short VT[32 * 136];     // V^T [d][kt], pad 136
  __shared__ unsigned short Ob[128 * 40];     // O row-major [q][d], pad 40
  int bn = blockIdx.x, tid = threadIdx.x;
  int b = bn >> 9, n = bn & 511;
  int lane = tid & 63, wave = tid >> 6;
  int l15 = lane & 15, quad = lane >> 4;
  int mt0 = wave * 2;

  const unsigned short* src = yin + n * 16384 + b * 4096;
  for (int idx = tid; idx < 4096; idx += 256) {
    int t = idx >> 5, c = idx & 31;
    unsigned short v = src[idx];
    hrow[t * 34 + c] = v;
    hfrag[((t >> 4) * 4 + (c >> 3)) * 128 + (t & 15) * 8 + (c & 7)] = v;
  }

  for (int L = 0; L < 2; ++L) {
    if (L) {
      __syncthreads();
      for (int idx = tid; idx < 4096; idx += 256) {
        int t = idx >> 5, c = idx & 31;
        hfrag[((t >> 4) * 4 + (c >> 3)) * 128 + (t & 15) * 8 + (c & 7)] =
            hrow[t * 34 + c];
      }
    }
    const float* wmat0 = wqg + L * 1024;
    const float* wmat1 = wkg + L * 1024;
    const float* wmat2 = wvg + L * 1024;
    const float* wmat3 = wog + L * 1024;
    short8 wf[4][2];
#pragma unroll
    for (int nt = 0; nt < 2; ++nt)
#pragma unroll
      for (int j = 0; j < 8; ++j) {
        int ri = (quad * 8 + j) * 32 + nt * 16 + l15;
        wf[0][nt][j] = (short)f2b(wmat0[ri] * 0.25f);  // scale folded into Q
        wf[1][nt][j] = (short)f2b(wmat1[ri]);
        wf[2][nt][j] = (short)f2b(wmat2[ri]);
        wf[3][nt][j] = (short)f2b(wmat3[ri]);
      }
    __syncthreads();
    // ---- projections; write K row-major, Q^T/V^T transposed (b64) ----
#pragma unroll
    for (int mm = 0; mm < 2; ++mm) {
      int mtq = mt0 + mm;
      short8 af = *(const short8*)&hfrag[(mtq * 4 + quad) * 128 + l15 * 8];
      int tbase = mtq * 16 + quad * 4;
#pragma unroll
      for (int nt = 0; nt < 2; ++nt) {
        float4v qa = MFMA32(af, wf[0][nt], (float4v)0.f);
        float4v ka = MFMA32(af, wf[1][nt], (float4v)0.f);
        float4v va = MFMA32(af, wf[2][nt], (float4v)0.f);
        int d = nt * 16 + l15;
#pragma unroll
        for (int r = 0; r < 4; ++r) Kb[(tbase + r) * 36 + d] = f2b(ka[r]);
        ushort4 qw, vw;
        qw.x = f2b(qa[0]); qw.y = f2b(qa[1]); qw.z = f2b(qa[2]); qw.w = f2b(qa[3]);
        vw.x = f2b(va[0]); vw.y = f2b(va[1]); vw.z = f2b(va[2]); vw.w = f2b(va[3]);
        *(ushort4*)&QT[d * 136 + tbase] = qw;
        *(ushort4*)&VT[d * 136 + tbase] = vw;
      }
    }
    __syncthreads();
    // ---- scores (S^T = K @ Q^T), softmax, PV (P^T C-frag == B16-frag) ----
    float4v oaccT[2][2];  // [mm][hh]: O^T C-frag (row d-local, col q)
#pragma unroll
    for (int mm = 0; mm < 2; ++mm)
#pragma unroll
      for (int hh = 0; hh < 2; ++hh) oaccT[mm][hh] = (float4v)0.f;
    for (int hh = 0; hh < 2; ++hh) {
#pragma unroll
      for (int mm = 0; mm < 2; ++mm) {
        int mtq = mt0 + mm;
        short4v qb;
#pragma unroll
        for (int jj = 0; jj < 4; ++jj)
          qb[jj] = (short)QT[(hh * 16 + quad * 4 + jj) * 136 + mtq * 16 + l15];
        float4v sacc[8];
#pragma unroll
        for (int st = 0; st < 8; ++st) {
          short4v ka = *(const short4v*)&Kb[(st * 16 + l15) * 36 + hh * 16 +
                                            quad * 4];
          sacc[st] = MFMA16A(ka, qb, (float4v)0.f);
        }
        // softmax over kt (8 st x 4 r in-thread + cross-quad shuffles)
        float mx = -1e30f;
#pragma unroll
        for (int st = 0; st < 8; ++st)
#pragma unroll
          for (int r = 0; r < 4; ++r) mx = fmaxf(mx, sacc[st][r]);
        mx = fmaxf(mx, __shfl_xor(mx, 16));
        mx = fmaxf(mx, __shfl_xor(mx, 32));
        float sum = 0.f;
#pragma unroll
        for (int st = 0; st < 8; ++st)
#pragma unroll
          for (int r = 0; r < 4; ++r) {
            float e = __expf(sacc[st][r] - mx);
            sacc[st][r] = e;
            sum += e;
          }
        sum += __shfl_xor(sum, 16);
        sum += __shfl_xor(sum, 32);
        float inv = 1.f / sum;
#pragma unroll
        for (int st = 0; st < 8; ++st) {
          short4v pb;
#pragma unroll
          for (int r = 0; r < 4; ++r) pb[r] = (short)f2b(sacc[st][r] * inv);
          short4v va = *(const short4v*)&VT[(hh * 16 + l15) * 136 + st * 16 +
                                            quad * 4];
          oaccT[mm][hh] = MFMA16A(va, pb, oaccT[mm][hh]);
        }
      }
    }
    // ---- O^T C-frag -> O row-major (b64, wave-local) ----
#pragma unroll
    for (int mm = 0; mm < 2; ++mm) {
      int mtq = mt0 + mm;
#pragma unroll
      for (int hh = 0; hh < 2; ++hh) {
        ushort4 ow;
        ow.x = f2b(oaccT[mm][hh][0]);
        ow.y = f2b(oaccT[mm][hh][1]);
        ow.z = f2b(oaccT[mm][hh][2]);
        ow.w = f2b(oaccT[mm][hh][3]);
        *(ushort4*)&Ob[(mtq * 16 + l15) * 40 + hh * 16 + quad * 4] = ow;
      }
    }
    // ---- output projection + residual + layernorm ----
    float gam0 = gg[L * 32 + l15], bet0 = bgb[L * 32 + l15];
    float gam1 = gg[L * 32 + 16 + l15], bet1 = bgb[L * 32 + 16 + l15];
#pragma unroll
    for (int mm = 0; mm < 2; ++mm) {
      int mtq = mt0 + mm;
      short8 ofa = *(const short8*)&Ob[(mtq * 16 + l15) * 40 + quad * 8];
      float4v racc0 = MFMA32(ofa, wf[3][0], (float4v)0.f);
      float4v racc1 = MFMA32(ofa, wf[3][1], (float4v)0.f);
#pragma unroll
      for (int r = 0; r < 4; ++r) {
        int t = mtq * 16 + quad * 4 + r;
        float v0 = racc0[r] + b2f(hrow[t * 34 + l15]);
        float v1 = racc1[r] + b2f(hrow[t * 34 + 16 + l15]);
        float s = v0 + v1;
        for (int m = 1; m < 16; m <<= 1) s += __shfl_xor(s, m);
        float mu = s * 0.03125f;
        float d0 = v0 - mu, d1 = v1 - mu;
        float q = d0 * d0 + d1 * d1;
        for (int m = 1; m < 16; m <<= 1) q += __shfl_xor(q, m);
        float rs = rsqrtf(q * 0.03125f + 1e-5f);
        float y0 = d0 * rs * gam0 + bet0;
        float y1 = d1 * rs * gam1 + bet1;
        if (L == 0) {
          hrow[t * 34 + l15] = f2b(y0);
          hrow[t * 34 + 16 + l15] = f2b(y1);
        } else {
          outp[((b * 128 + t) * 512 + n) * 32 + l15] = y0;
          outp[((b * 128 + t) * 512 + n) * 32 + 16 + l15] = y1;
        }
      }
    }
  }
}

extern "C" void kernel_launch(void* const* d_in, const int* in_sizes, int n_in,
                              void* d_out, int out_size, void* d_ws, size_t ws_size,
                              hipStream_t stream) {
  const float* x    = (const float*)d_in[0];
  const float* emb  = (const float*)d_in[2];
  const float* adj  = (const float*)d_in[3];
  const float* gw   = (const float*)d_in[4];
  const float* gb   = (const float*)d_in[5];
  const float* tw1  = (const float*)d_in[6];
  const float* tb1  = (const float*)d_in[7];
  const float* tw2  = (const float*)d_in[8];
  const float* tb2  = (const float*)d_in[9];
  const float* wq   = (const float*)d_in[10];
  const float* wk   = (const float*)d_in[11];
  const float* wv   = (const float*)d_in[12];
  const float* wo   = (const float*)d_in[13];
  const float* tg   = (const float*)d_in[14];
  const float* tbb  = (const float*)d_in[15];
  float* outp = (float*)d_out;

  char* p = (char*)d_ws;
  unsigned short* Sb  = (unsigned short*)p; p += 1048576;
  unsigned short* W8  = (unsigned short*)p; p += 9437184;
  float* biasn        = (float*)p;          p += 196608;
  float* G            = (float*)p;          p += 67108864;
  unsigned short* H8a = (unsigned short*)p; p += 16777216;
  unsigned short* H8b = (unsigned short*)p; p += 16777216;
  unsigned short* Hra = (unsigned short*)p; p += 16777216;
  unsigned short* Hrb = (unsigned short*)p; p += 16777216;
  unsigned short* Wt  = (unsigned short*)p; p += 36864;  // ~145.0 MB total

  prep_supports<<<dim3(512), dim3(256), 0, stream>>>(adj, Sb);
  prep_w_kernel<<<dim3(1536), dim3(256), 0, stream>>>(emb, gw, gb, W8, biasn);
  prep_tw<<<dim3(6), dim3(256), 0, stream>>>(tw1, tw2, Wt);
  conv_x<<<dim3(512), dim3(256), 0, stream>>>(x, H8a, Hra);

  gcn_phaseA<<<dim3(1024), dim3(256), 0, stream>>>(Sb, H8a, G);
  gcn_phaseB<<<dim3(1024), dim3(256), 0, stream>>>(
      Hra, G, W8, biasn, H8b, Hrb, (unsigned short*)nullptr);
  gcn_phaseA<<<dim3(1024), dim3(256), 0, stream>>>(Sb, H8b, G);
  gcn_phaseB<<<dim3(1024), dim3(256), 0, stream>>>(
      Hrb, G, W8 + 1572864, biasn + 16384, H8a, Hra, (unsigned short*)nullptr);
  gcn_phaseA<<<dim3(1024), dim3(256), 0, stream>>>(Sb, H8a, G);
  gcn_phaseB<<<dim3(1024), dim3(256), 0, stream>>>(
      Hra, G, W8 + 3145728, biasn + 32768, (unsigned short*)nullptr,
      (unsigned short*)nullptr, H8b);

  tcn_kernel<<<dim3(512), dim3(256), 0, stream>>>(H8b, H8a, Wt, tb1, tb2);
  attn_kernel<<<dim3(2048), dim3(256), 0, stream>>>(H8a, outp, wq, wk, wv, wo,
                                                    tg, tbb);
}

// Round 7
// 438.865 us; speedup vs baseline: 7.4275x; 1.0599x over previous
//
#include <hip/hip_runtime.h>
#include <hip/hip_bf16.h>

// B=4, T=128, N=512, D=32, CHEB_K=3, EMB=10, HEADS=2, TA_LAYERS=2, GCN_NUM=3,
// TCN_BLOCKS=3, KSIZE=3.  Inputs/outputs fp32; internal bf16 + MFMA.

typedef __attribute__((ext_vector_type(8))) short short8;
typedef __attribute__((ext_vector_type(4))) short short4v;
typedef __attribute__((ext_vector_type(4))) float float4v;

#define MFMA32(a, b, c) __builtin_amdgcn_mfma_f32_16x16x32_bf16((a), (b), (c), 0, 0, 0)
#if defined(__has_builtin)
#if __has_builtin(__builtin_amdgcn_mfma_f32_16x16x16_bf16)
#define MFMA16A(a, b, c) __builtin_amdgcn_mfma_f32_16x16x16_bf16((a), (b), (c), 0, 0, 0)
#endif
#endif
#ifndef MFMA16A
#define MFMA16A(a, b, c) __builtin_amdgcn_mfma_f32_16x16x16bf16_1k((a), (b), (c), 0, 0, 0)
#endif

__device__ __forceinline__ unsigned short f2b(float f) {
  unsigned int x = __float_as_uint(f);
  unsigned int r = (x + 0x7fffu + ((x >> 16) & 1u)) >> 16;
  return (unsigned short)r;
}
__device__ __forceinline__ float b2f(unsigned short u) {
  return __uint_as_float(((unsigned int)u) << 16);
}
// packed fp32x2 -> bf16x2 (v_cvt_pk_bf16_f32 on gfx950), RNE
__device__ __forceinline__ unsigned int f2b2(float lo, float hi) {
  union { __hip_bfloat162 h; unsigned int u; } cv;
  cv.h = __float22bfloat162_rn(make_float2(lo, hi));
  return cv.u;
}
__device__ __forceinline__ ushort4 f2b4(float a, float b, float c, float d) {
  union { unsigned int u[2]; ushort4 s; } cv;
  cv.u[0] = f2b2(a, b);
  cv.u[1] = f2b2(c, d);
  return cv.s;
}

// ---------------- prep: supports in bf16 ----------------
__global__ void __launch_bounds__(256) prep_supports(
    const float* __restrict__ adj, unsigned short* __restrict__ Sb) {
  __shared__ float arow[512];
  int n = blockIdx.x, tid = threadIdx.x;
  for (int m = tid; m < 512; m += 256) {
    float v = adj[n * 512 + m];
    arow[m] = v;
    Sb[n * 512 + m] = f2b(v);
  }
  __syncthreads();
  for (int m = tid; m < 512; m += 256) {
    float acc = 0.f;
    for (int p = 0; p < 512; ++p) acc += arow[p] * adj[p * 512 + m];
    Sb[(512 + n) * 512 + m] = f2b(2.f * acc - (m == n ? 1.f : 0.f));
  }
}

// ---------------- prep: per-node GCN weights -> bf16 B-frag layout -------
__global__ void __launch_bounds__(256) prep_w_kernel(
    const float* __restrict__ emb, const float* __restrict__ gw,
    const float* __restrict__ gb,
    unsigned short* __restrict__ W8, float* __restrict__ biasn) {
  int bid = blockIdx.x;  // 0..1535
  int i = bid >> 9, n = bid & 511, tid = threadIdx.x;
  float ev[10];
#pragma unroll
  for (int e = 0; e < 10; ++e) ev[e] = emb[n * 10 + e];
  for (int idx = tid; idx < 3072; idx += 256) {
    int s = idx >> 10, c = (idx >> 5) & 31, o = idx & 31;
    float acc = 0.f;
#pragma unroll
    for (int e = 0; e < 10; ++e) acc += ev[e] * gw[(i * 10 + e) * 3072 + idx];
    W8[((i * 512 + n) * 3 + s) * 1024 + (c >> 3) * 256 + o * 8 + (c & 7)] =
        f2b(acc);
  }
  if (tid < 32) {
    float acc = 0.f;
#pragma unroll
    for (int e = 0; e < 10; ++e) acc += ev[e] * gb[(i * 10 + e) * 32 + tid];
    biasn[(i * 512 + n) * 32 + tid] = acc;
  }
}

// ---------------- prep: TCN weights -> bf16 A-frag layout ----------------
__global__ void __launch_bounds__(256) prep_tw(
    const float* __restrict__ w1g, const float* __restrict__ w2g,
    unsigned short* __restrict__ Wt) {
  int bid = blockIdx.x;  // 6 = blk(3) x conv(2)
  int blk = bid >> 1, conv = bid & 1;
  const float* w = (conv ? w2g : w1g) + blk * 3072;
  for (int idx = threadIdx.x; idx < 3072; idx += 256) {
    int kk = idx >> 10, rem = idx & 1023;
    int o = rem >> 5, c = rem & 31;
    Wt[bid * 3072 + idx] = f2b(w[o * 96 + c * 3 + kk]);
  }
}

// ---------------- x -> H8 swizzled + Hrm row-major bf16 ----------------
__global__ void __launch_bounds__(256) conv_x(
    const float* __restrict__ x, unsigned short* __restrict__ H8,
    unsigned short* __restrict__ Hrm) {
  int bid = blockIdx.x;  // 512 = nblk(64) x btc(8)
  int nblk = bid >> 3, btc = bid & 7;
  int tid = threadIdx.x, s = tid >> 5, c = tid & 31;
  for (int bti = 0; bti < 64; ++bti) {
    int bt = btc * 64 + bti;
    float v = x[bt * 16384 + nblk * 256 + tid];
    unsigned short bv = f2b(v);
    H8[nblk * 131072 + (bt * 32 + c) * 8 + s] = bv;
    Hrm[(nblk * 8 + s) * 16384 + bt * 32 + c] = bv;
  }
}

// ---------------- GCN phase A: G = S @ H  (MFMA, bf16 out) --------------
#define AST 40
__global__ void __launch_bounds__(256) gcn_phaseA(
    const unsigned short* __restrict__ Sb,
    const unsigned short* __restrict__ H8,
    unsigned short* __restrict__ G) {
  __shared__ unsigned short As[128 * AST];
  __shared__ unsigned short Bs[4096];
  int bid = blockIdx.x;  // 1024 = jt(128) x mt(8)
  int mt = bid & 7, jt = bid >> 3;
  int m0 = mt * 128, j0 = jt * 128;
  int tid = threadIdx.x;
  int wave = tid >> 6, lane = tid & 63;
  int wm = wave >> 1, wj = wave & 1;
  int l15 = lane & 15, quad = lane >> 4;
  float4v acc[4][4];
#pragma unroll
  for (int a = 0; a < 4; ++a)
#pragma unroll
    for (int b = 0; b < 4; ++b) acc[a][b] = (float4v)0.f;
  for (int nc = 0; nc < 512; nc += 32) {
#pragma unroll
    for (int p = 0; p < 2; ++p) {
      int q = tid + p * 256;
      int m = q >> 2, seg = q & 3;
      *(uint4*)&As[m * AST + seg * 8] =
          *(const uint4*)&Sb[(m0 + m) * 512 + nc + seg * 8];
    }
    const unsigned short* hb = H8 + (nc >> 3) * 131072 + j0 * 8;
#pragma unroll
    for (int p = 0; p < 2; ++p) {
      int q = tid + p * 256;
      int nb = q >> 7, rem = q & 127;
      *(uint4*)&Bs[nb * 1024 + rem * 8] =
          *(const uint4*)&hb[nb * 131072 + rem * 8];
    }
    __syncthreads();
    short8 af[4], bfr[4];
#pragma unroll
    for (int mi = 0; mi < 4; ++mi)
      af[mi] = *(const short8*)&As[(wm * 64 + mi * 16 + l15) * AST + quad * 8];
#pragma unroll
    for (int ji = 0; ji < 4; ++ji)
      bfr[ji] = *(const short8*)&Bs[quad * 1024 + (wj * 64 + ji * 16 + l15) * 8];
#pragma unroll
    for (int mi = 0; mi < 4; ++mi)
#pragma unroll
      for (int ji = 0; ji < 4; ++ji)
        acc[mi][ji] = MFMA32(af[mi], bfr[ji], acc[mi][ji]);
    __syncthreads();
  }
#pragma unroll
  for (int mi = 0; mi < 4; ++mi)
#pragma unroll
    for (int ji = 0; ji < 4; ++ji) {
      int j = j0 + wj * 64 + ji * 16 + l15;
#pragma unroll
      for (int r = 0; r < 4; ++r) {
        int m = m0 + wm * 64 + mi * 16 + quad * 4 + r;
        G[m * 16384 + j] = f2b(acc[mi][ji][r]);
      }
    }
}

// ---------------- GCN phase B: per-node MFMA weight apply ----------------
__global__ void __launch_bounds__(256) gcn_phaseB(
    const unsigned short* __restrict__ Hrm, const unsigned short* __restrict__ G,
    const unsigned short* __restrict__ W8, const float* __restrict__ biasn,
    unsigned short* __restrict__ H8out, unsigned short* __restrict__ Hrmout,
    unsigned short* __restrict__ tcnout) {
  int bid = blockIdx.x;  // 1024 = n(512) x bh(2)
  int n = bid >> 1, bh = bid & 1;
  int tid = threadIdx.x;
  int lane = tid & 63, wave = tid >> 6, l15 = lane & 15, quad = lane >> 4;
  short8 wb[3][2];
#pragma unroll
  for (int s = 0; s < 3; ++s)
#pragma unroll
    for (int nt = 0; nt < 2; ++nt)
      wb[s][nt] = *(const short8*)&W8[(n * 3 + s) * 1024 + quad * 256 +
                                      (nt * 16 + l15) * 8];
  float b0 = biasn[n * 32 + l15], b1 = biasn[n * 32 + 16 + l15];
  int n8base = (n >> 3) * 131072 + (n & 7);
#pragma unroll
  for (int mi = 0; mi < 4; ++mi) {
    int bt0 = bh * 256 + wave * 64 + mi * 16;
    int btl = bt0 + l15;
    short8 a0 = *(const short8*)&Hrm[n * 16384 + btl * 32 + quad * 8];
    short8 a1 = *(const short8*)&G[n * 16384 + btl * 32 + quad * 8];
    short8 a2 = *(const short8*)&G[(512 + n) * 16384 + btl * 32 + quad * 8];
    float4v acc0 = MFMA32(a0, wb[0][0], (float4v)0.f);
    acc0 = MFMA32(a1, wb[1][0], acc0);
    acc0 = MFMA32(a2, wb[2][0], acc0);
    float4v acc1 = MFMA32(a0, wb[0][1], (float4v)0.f);
    acc1 = MFMA32(a1, wb[1][1], acc1);
    acc1 = MFMA32(a2, wb[2][1], acc1);
#pragma unroll
    for (int r = 0; r < 4; ++r) {
      int bt = bt0 + quad * 4 + r;
      unsigned short v0 = f2b(acc0[r] + b0);
      unsigned short v1 = f2b(acc1[r] + b1);
      if (tcnout) {
        int bb = bt >> 7, t = bt & 127;
        int o0 = l15, o1 = 16 + l15;
        tcnout[n * 16384 + bb * 4096 + (o0 >> 3) * 1024 + t * 8 + (o0 & 7)] = v0;
        tcnout[n * 16384 + bb * 4096 + (o1 >> 3) * 1024 + t * 8 + (o1 & 7)] = v1;
      } else {
        H8out[n8base + (bt * 32 + l15) * 8] = v0;
        H8out[n8base + (bt * 32 + 16 + l15) * 8] = v1;
        Hrmout[n * 16384 + bt * 32 + l15] = v0;
        Hrmout[n * 16384 + bt * 32 + 16 + l15] = v1;
      }
    }
  }
}

// ---------------- TCN: wave-per-(b,n), full MFMA, no barriers ----------
__global__ void __launch_bounds__(256) tcn_kernel(
    const unsigned short* __restrict__ Yin, unsigned short* __restrict__ yout,
    const unsigned short* __restrict__ Wt,
    const float* __restrict__ b1g, const float* __restrict__ b2g) {
  __shared__ unsigned short Y8[4][4352];
  __shared__ unsigned short O8[4][4352];
  int tid = threadIdx.x, wave = tid >> 6, lane = tid & 63;
  int l15 = lane & 15, quad = lane >> 4;
  int n = blockIdx.x, b = wave;
  unsigned short* y8 = &Y8[wave][0];
  unsigned short* o8 = &O8[wave][0];
  {
    int cg = lane >> 4, t = (lane >> 1) & 7, half = lane & 1;
    ushort4 z = {0, 0, 0, 0};
    *(ushort4*)&y8[(cg * 136 + t) * 8 + half * 4] = z;
    *(ushort4*)&o8[(cg * 136 + t) * 8 + half * 4] = z;
  }
  const unsigned short* src = Yin + n * 16384 + b * 4096;
#pragma unroll
  for (int p = 0; p < 8; ++p) {
    int e = p * 64 + lane;
    int cg = e >> 7, t = e & 127;
    *(uint4*)&y8[(cg * 136 + t + 8) * 8] = *(const uint4*)&src[e * 8];
  }
  for (int blk = 0; blk < 3; ++blk) {
    int dil = 1 << blk;
    for (int conv = 0; conv < 2; ++conv) {
      const unsigned short* wbase = Wt + ((blk * 2 + conv) * 3) * 1024;
      short8 af[2][3];
#pragma unroll
      for (int mt = 0; mt < 2; ++mt)
#pragma unroll
        for (int kk = 0; kk < 3; ++kk)
          af[mt][kk] = *(const short8*)&wbase[kk * 1024 +
                                              (mt * 16 + l15) * 32 + quad * 8];
      const float* bias = (conv ? b2g : b1g) + blk * 32;
      float4 bs0 = *(const float4*)&bias[quad * 4];
      float4 bs1 = *(const float4*)&bias[16 + quad * 4];
      float bb0[4] = {bs0.x, bs0.y, bs0.z, bs0.w};
      float bb1[4] = {bs1.x, bs1.y, bs1.z, bs1.w};
      const unsigned short* rbuf = conv ? o8 : y8;
#pragma unroll 2
      for (int nt = 0; nt < 8; ++nt) {
        float4v acc0 = (float4v)0.f, acc1 = (float4v)0.f;
#pragma unroll
        for (int kk = 0; kk < 3; ++kk) {
          int tb = nt * 16 + l15 + 8 - (2 - kk) * dil;
          short8 bf = *(const short8*)&rbuf[(quad * 136 + tb) * 8];
          acc0 = MFMA32(af[0][kk], bf, acc0);
          acc1 = MFMA32(af[1][kk], bf, acc1);
        }
        int t8 = nt * 16 + l15 + 8;
        int og0 = (quad >> 1), ci0 = (quad & 1) * 4;
        if (conv == 0) {
          ushort4 w0 = f2b4(fmaxf(acc0[0] + bb0[0], 0.f),
                            fmaxf(acc0[1] + bb0[1], 0.f),
                            fmaxf(acc0[2] + bb0[2], 0.f),
                            fmaxf(acc0[3] + bb0[3], 0.f));
          ushort4 w1 = f2b4(fmaxf(acc1[0] + bb1[0], 0.f),
                            fmaxf(acc1[1] + bb1[1], 0.f),
                            fmaxf(acc1[2] + bb1[2], 0.f),
                            fmaxf(acc1[3] + bb1[3], 0.f));
          *(ushort4*)&o8[((og0)*136 + t8) * 8 + ci0] = w0;
          *(ushort4*)&o8[((2 + og0) * 136 + t8) * 8 + ci0] = w1;
        } else {
          ushort4 y0 = *(const ushort4*)&y8[((og0)*136 + t8) * 8 + ci0];
          ushort4 y1 = *(const ushort4*)&y8[((2 + og0) * 136 + t8) * 8 + ci0];
          ushort4 w0 = f2b4(
              fmaxf(fmaxf(acc0[0] + bb0[0], 0.f) + b2f(y0.x), 0.f),
              fmaxf(fmaxf(acc0[1] + bb0[1], 0.f) + b2f(y0.y), 0.f),
              fmaxf(fmaxf(acc0[2] + bb0[2], 0.f) + b2f(y0.z), 0.f),
              fmaxf(fmaxf(acc0[3] + bb0[3], 0.f) + b2f(y0.w), 0.f));
          ushort4 w1 = f2b4(
              fmaxf(fmaxf(acc1[0] + bb1[0], 0.f) + b2f(y1.x), 0.f),
              fmaxf(fmaxf(acc1[1] + bb1[1], 0.f) + b2f(y1.y), 0.f),
              fmaxf(fmaxf(acc1[2] + bb1[2], 0.f) + b2f(y1.z), 0.f),
              fmaxf(fmaxf(acc1[3] + bb1[3], 0.f) + b2f(y1.w), 0.f));
          *(ushort4*)&y8[((og0)*136 + t8) * 8 + ci0] = w0;
          *(ushort4*)&y8[((2 + og0) * 136 + t8) * 8 + ci0] = w1;
        }
      }
    }
  }
  unsigned short* dst = yout + n * 16384 + b * 4096;
#pragma unroll
  for (int p = 0; p < 8; ++p) {
    int e = p * 64 + lane;
    int og = e >> 7, t = e & 127;
    *(uint4*)&dst[t * 32 + og * 8] = *(const uint4*)&y8[(og * 136 + t + 8) * 8];
  }
}

// ---------------- attention: S^T trick, single hfrag staging ------------
__global__ void __launch_bounds__(256) attn_kernel(
    const unsigned short* __restrict__ yin,  // bf16 [n][b][t*32+d]
    float* __restrict__ outp,
    const float* __restrict__ wqg, const float* __restrict__ wkg,
    const float* __restrict__ wvg, const float* __restrict__ wog,
    const float* __restrict__ gg, const float* __restrict__ bgb) {
  __shared__ unsigned short hfrag[4096];      // h in A32-frag layout (+residual)
  __shared__ unsigned short Kb[128 * 36];     // K row-major [t][d], pad 36
  __shared__ unsigned short QT[32 * 136];     // Q^T [d][t], pad 136
  __shared__ unsigned short VT[32 * 136];     // V^T [d][kt], pad 136
  __shared__ unsigned short Ob[128 * 40];     // O row-major [q][d], pad 40
  int bn = blockIdx.x, tid = threadIdx.x;
  int b = bn >> 9, n = bn & 511;
  int lane = tid & 63, wave = tid >> 6;
  int l15 = lane & 15, quad = lane >> 4;
  int mt0 = wave * 2;

  const unsigned short* src = yin + n * 16384 + b * 4096;
  for (int idx = tid; idx < 4096; idx += 256) {
    int t = idx >> 5, c = idx & 31;
    hfrag[((t >> 4) * 4 + (c >> 3)) * 128 + (t & 15) * 8 + (c & 7)] = src[idx];
  }

  for (int L = 0; L < 2; ++L) {
    const float* wmat0 = wqg + L * 1024;
    const float* wmat1 = wkg + L * 1024;
    const float* wmat2 = wvg + L * 1024;
    const float* wmat3 = wog + L * 1024;
    short8 wf[4][2];
#pragma unroll
    for (int nt = 0; nt < 2; ++nt)
#pragma unroll
      for (int j = 0; j < 8; ++j) {
        int ri = (quad * 8 + j) * 32 + nt * 16 + l15;
        wf[0][nt][j] = (short)f2b(wmat0[ri] * 0.25f);  // scale folded into Q
        wf[1][nt][j] = (short)f2b(wmat1[ri]);
        wf[2][nt][j] = (short)f2b(wmat2[ri]);
        wf[3][nt][j] = (short)f2b(wmat3[ri]);
      }
    __syncthreads();  // L0: hfrag staged; L1: Kb/QT/VT reads of L0 done
    // ---- projections; write K row-major, Q^T/V^T transposed (b64) ----
#pragma unroll
    for (int mm = 0; mm < 2; ++mm) {
      int mtq = mt0 + mm;
      short8 af = *(const short8*)&hfrag[(mtq * 4 + quad) * 128 + l15 * 8];
      int tbase = mtq * 16 + quad * 4;
#pragma unroll
      for (int nt = 0; nt < 2; ++nt) {
        float4v qa = MFMA32(af, wf[0][nt], (float4v)0.f);
        float4v ka = MFMA32(af, wf[1][nt], (float4v)0.f);
        float4v va = MFMA32(af, wf[2][nt], (float4v)0.f);
        int d = nt * 16 + l15;
#pragma unroll
        for (int r = 0; r < 4; ++r) Kb[(tbase + r) * 36 + d] = f2b(ka[r]);
        *(ushort4*)&QT[d * 136 + tbase] = f2b4(qa[0], qa[1], qa[2], qa[3]);
        *(ushort4*)&VT[d * 136 + tbase] = f2b4(va[0], va[1], va[2], va[3]);
      }
    }
    __syncthreads();  // frags ready
    // ---- scores (S^T = K @ Q^T), softmax, PV (P^T C-frag == B16-frag) ----
    float4v oaccT[2][2];
#pragma unroll
    for (int mm = 0; mm < 2; ++mm)
#pragma unroll
      for (int hh = 0; hh < 2; ++hh) oaccT[mm][hh] = (float4v)0.f;
    for (int hh = 0; hh < 2; ++hh) {
#pragma unroll
      for (int mm = 0; mm < 2; ++mm) {
        int mtq = mt0 + mm;
        short4v qb;
#pragma unroll
        for (int jj = 0; jj < 4; ++jj)
          qb[jj] = (short)QT[(hh * 16 + quad * 4 + jj) * 136 + mtq * 16 + l15];
        float4v sacc[8];
#pragma unroll
        for (int st = 0; st < 8; ++st) {
          short4v ka = *(const short4v*)&Kb[(st * 16 + l15) * 36 + hh * 16 +
                                            quad * 4];
          sacc[st] = MFMA16A(ka, qb, (float4v)0.f);
        }
        float mx = -1e30f;
#pragma unroll
        for (int st = 0; st < 8; ++st)
#pragma unroll
          for (int r = 0; r < 4; ++r) mx = fmaxf(mx, sacc[st][r]);
        mx = fmaxf(mx, __shfl_xor(mx, 16));
        mx = fmaxf(mx, __shfl_xor(mx, 32));
        float sum = 0.f;
#pragma unroll
        for (int st = 0; st < 8; ++st)
#pragma unroll
          for (int r = 0; r < 4; ++r) {
            float e = __expf(sacc[st][r] - mx);
            sacc[st][r] = e;
            sum += e;
          }
        sum += __shfl_xor(sum, 16);
        sum += __shfl_xor(sum, 32);
        float inv = 1.f / sum;
#pragma unroll
        for (int st = 0; st < 8; ++st) {
          union { unsigned int u[2]; short4v s; } pv;
          pv.u[0] = f2b2(sacc[st][0] * inv, sacc[st][1] * inv);
          pv.u[1] = f2b2(sacc[st][2] * inv, sacc[st][3] * inv);
          short4v va = *(const short4v*)&VT[(hh * 16 + l15) * 136 + st * 16 +
                                            quad * 4];
          oaccT[mm][hh] = MFMA16A(va, pv.s, oaccT[mm][hh]);
        }
      }
    }
    // ---- O^T C-frag -> O row-major (b64, wave-local) ----
#pragma unroll
    for (int mm = 0; mm < 2; ++mm) {
      int mtq = mt0 + mm;
#pragma unroll
      for (int hh = 0; hh < 2; ++hh)
        *(ushort4*)&Ob[(mtq * 16 + l15) * 40 + hh * 16 + quad * 4] =
            f2b4(oaccT[mm][hh][0], oaccT[mm][hh][1], oaccT[mm][hh][2],
                 oaccT[mm][hh][3]);
    }
    // ---- output projection + residual + layernorm ----
    float gam0 = gg[L * 32 + l15], bet0 = bgb[L * 32 + l15];
    float gam1 = gg[L * 32 + 16 + l15], bet1 = bgb[L * 32 + 16 + l15];
#pragma unroll
    for (int mm = 0; mm < 2; ++mm) {
      int mtq = mt0 + mm;
      short8 ofa = *(const short8*)&Ob[(mtq * 16 + l15) * 40 + quad * 8];
      float4v racc0 = MFMA32(ofa, wf[3][0], (float4v)0.f);
      float4v racc1 = MFMA32(ofa, wf[3][1], (float4v)0.f);
      int hi0 = (mtq * 4 + (l15 >> 3)) * 128 + (l15 & 7);
      int hi1 = (mtq * 4 + 2 + (l15 >> 3)) * 128 + (l15 & 7);
#pragma unroll
      for (int r = 0; r < 4; ++r) {
        int t = mtq * 16 + quad * 4 + r;
        int ro = (quad * 4 + r) * 8;
        float v0 = racc0[r] + b2f(hfrag[hi0 + ro]);
        float v1 = racc1[r] + b2f(hfrag[hi1 + ro]);
        float s = v0 + v1;
        for (int m = 1; m < 16; m <<= 1) s += __shfl_xor(s, m);
        float mu = s * 0.03125f;
        float d0 = v0 - mu, d1 = v1 - mu;
        float q = d0 * d0 + d1 * d1;
        for (int m = 1; m < 16; m <<= 1) q += __shfl_xor(q, m);
        float rs = rsqrtf(q * 0.03125f + 1e-5f);
        float y0 = d0 * rs * gam0 + bet0;
        float y1 = d1 * rs * gam1 + bet1;
        if (L == 0) {
          hfrag[hi0 + ro] = f2b(y0);  // wave-local rows; no barrier needed
          hfrag[hi1 + ro] = f2b(y1);
        } else {
          outp[((b * 128 + t) * 512 + n) * 32 + l15] = y0;
          outp[((b * 128 + t) * 512 + n) * 32 + 16 + l15] = y1;
        }
      }
    }
  }
}

extern "C" void kernel_launch(void* const* d_in, const int* in_sizes, int n_in,
                              void* d_out, int out_size, void* d_ws, size_t ws_size,
                              hipStream_t stream) {
  const float* x    = (const float*)d_in[0];
  const float* emb  = (const float*)d_in[2];
  const float* adj  = (const float*)d_in[3];
  const float* gw   = (const float*)d_in[4];
  const float* gb   = (const float*)d_in[5];
  const float* tw1  = (const float*)d_in[6];
  const float* tb1  = (const float*)d_in[7];
  const float* tw2  = (const float*)d_in[8];
  const float* tb2  = (const float*)d_in[9];
  const float* wq   = (const float*)d_in[10];
  const float* wk   = (const float*)d_in[11];
  const float* wv   = (const float*)d_in[12];
  const float* wo   = (const float*)d_in[13];
  const float* tg   = (const float*)d_in[14];
  const float* tbb  = (const float*)d_in[15];
  float* outp = (float*)d_out;

  char* p = (char*)d_ws;
  unsigned short* Sb  = (unsigned short*)p; p += 1048576;
  unsigned short* W8  = (unsigned short*)p; p += 9437184;
  float* biasn        = (float*)p;          p += 196608;
  unsigned short* G   = (unsigned short*)p; p += 33554432;  // bf16 now
  unsigned short* H8a = (unsigned short*)p; p += 16777216;
  unsigned short* H8b = (unsigned short*)p; p += 16777216;
  unsigned short* Hra = (unsigned short*)p; p += 16777216;
  unsigned short* Hrb = (unsigned short*)p; p += 16777216;
  unsigned short* Wt  = (unsigned short*)p; p += 36864;  // ~111.4 MB total

  prep_supports<<<dim3(512), dim3(256), 0, stream>>>(adj, Sb);
  prep_w_kernel<<<dim3(1536), dim3(256), 0, stream>>>(emb, gw, gb, W8, biasn);
  prep_tw<<<dim3(6), dim3(256), 0, stream>>>(tw1, tw2, Wt);
  conv_x<<<dim3(512), dim3(256), 0, stream>>>(x, H8a, Hra);

  gcn_phaseA<<<dim3(1024), dim3(256), 0, stream>>>(Sb, H8a, G);
  gcn_phaseB<<<dim3(1024), dim3(256), 0, stream>>>(
      Hra, G, W8, biasn, H8b, Hrb, (unsigned short*)nullptr);
  gcn_phaseA<<<dim3(1024), dim3(256), 0, stream>>>(Sb, H8b, G);
  gcn_phaseB<<<dim3(1024), dim3(256), 0, stream>>>(
      Hrb, G, W8 + 1572864, biasn + 16384, H8a, Hra, (unsigned short*)nullptr);
  gcn_phaseA<<<dim3(1024), dim3(256), 0, stream>>>(Sb, H8a, G);
  gcn_phaseB<<<dim3(1024), dim3(256), 0, stream>>>(
      Hra, G, W8 + 3145728, biasn + 32768, (unsigned short*)nullptr,
      (unsigned short*)nullptr, H8b);

  tcn_kernel<<<dim3(512), dim3(256), 0, stream>>>(H8b, H8a, Wt, tb1, tb2);
  attn_kernel<<<dim3(2048), dim3(256), 0, stream>>>(H8a, outp, wq, wk, wv, wo,
                                                    tg, tbb);
}